// Round 9
// baseline (210.160 us; speedup 1.0000x reference)
//
#include <hip/hip_runtime.h>

typedef __bf16 v8bf __attribute__((ext_vector_type(8)));
typedef float  v4f  __attribute__((ext_vector_type(4)));
typedef float  v16f __attribute__((ext_vector_type(16)));
typedef unsigned short u16;

__device__ __forceinline__ u16 f2bf(float f){
  __bf16 h = (__bf16)f;
  union { __bf16 h; u16 u; } c; c.h = h; return c.u;
}
__device__ __forceinline__ v4f v4zero(){ v4f z; z[0]=0.f; z[1]=0.f; z[2]=0.f; z[3]=0.f; return z; }

#define MFMA16(a,b,c) __builtin_amdgcn_mfma_f32_16x16x32_bf16((a),(b),(c),0,0,0)
#define MFMA32(a,b,c) __builtin_amdgcn_mfma_f32_32x32x16_bf16((a),(b),(c),0,0,0)

// async global->LDS, 16B per lane; LDS dest = wave-uniform base + lane*16
__device__ __forceinline__ void gl_lds16(const u16* g, u16* l){
  __builtin_amdgcn_global_load_lds((const __attribute__((address_space(1))) void*)g,
                                   (__attribute__((address_space(3))) void*)l, 16, 0, 0);
}

// v_cvt_pk_bf16_f32: pack two f32 -> one u32 of 2 bf16 (no builtin on gfx950)
__device__ __forceinline__ unsigned int pkbf(float lo, float hi){
  unsigned int r;
  asm("v_cvt_pk_bf16_f32 %0, %1, %2" : "=v"(r) : "v"(lo), "v"(hi));
  return r;
}

// ============ f32 -> bf16 bulk convert, both weight tensors in one launch ============
__global__ __launch_bounds__(256) void cvt2_kernel(const float* __restrict__ a, u16* __restrict__ da, int na,
                                                   const float* __restrict__ b, u16* __restrict__ db, int nb){
  int i = (blockIdx.x*256 + threadIdx.x)*4;
  const float* s; u16* d; int off;
  if (i < na){ s = a; d = da; off = i; }
  else { off = i - na; if (off >= nb) return; s = b; d = db; }
  float4 v = *(const float4*)(s + off);
  ushort4 o;
  o.x = f2bf(v.x); o.y = f2bf(v.y); o.z = f2bf(v.z); o.w = f2bf(v.w);
  *(ushort4*)(d + off) = o;
}

// ============ Fused GroupNorm: stats + apply + transpose in one kernel ============
__global__ __launch_bounds__(256) void gn_fused_kernel(const float* __restrict__ x, const float* __restrict__ nw,
                                                       const float* __restrict__ nb, u16* __restrict__ h_t){
  __shared__ float xs[16*1028 + 16];
  const int bg = blockIdx.x, b = bg >> 5, g = bg & 31, c0 = g*16;
  const int tid = threadIdx.x;
  const float* base = x + (size_t)(b*512 + c0)*1024;

  float s = 0.f, ss = 0.f;
  #pragma unroll
  for (int it = 0; it < 16; ++it){
    float4 v = *(const float4*)(base + it*1024 + tid*4);
    s  += v.x + v.y + v.z + v.w;
    ss += v.x*v.x + v.y*v.y + v.z*v.z + v.w*v.w;
    *(float4*)(xs + it*1028 + tid*4) = v;
  }
  #pragma unroll
  for (int off = 32; off > 0; off >>= 1){ s += __shfl_down(s, off); ss += __shfl_down(ss, off); }
  float* red = xs + 16*1028;
  int w = tid >> 6;
  if ((tid & 63) == 0){ red[w] = s; red[4+w] = ss; }
  __syncthreads();
  if (tid == 0){
    float S  = red[0]+red[1]+red[2]+red[3];
    float SS = red[4]+red[5]+red[6]+red[7];
    float mean = S * (1.f/16384.f);
    float var  = SS * (1.f/16384.f) - mean*mean;
    red[8] = mean;
    red[9] = rsqrtf(var + 1e-5f);
  }
  __syncthreads();
  const float mean = red[8], rstd = red[9];

  const int half = tid & 1, nbase = tid >> 1;
  float wv[8], bv[8];
  #pragma unroll
  for (int cl = 0; cl < 8; ++cl){
    int c = c0 + half*8 + cl;
    wv[cl] = nw[c] * rstd;
    bv[cl] = nb[c] - mean * wv[cl];
  }
  #pragma unroll
  for (int p = 0; p < 8; ++p){
    int n = nbase + p*128;
    alignas(16) u16 tmp[8];
    #pragma unroll
    for (int cl = 0; cl < 8; ++cl)
      tmp[cl] = f2bf(xs[(half*8 + cl)*1028 + n] * wv[cl] + bv[cl]);
    *(int4*)(h_t + ((size_t)b*1024 + n)*512 + c0 + half*8) = *(int4*)tmp;
  }
}

// ============ Fused QKV GEMM, double-buffered BK=32, 1 barrier/iter, 3 blocks/CU ============
// 768 blocks: with (256,2) residency was 1.5 occupancy rounds (256-block tail at half
// machine). LDS 48KB fits 3/CU (144KB <= 160KB); (256,3) -> exactly one round, and a
// 3rd drifting block fills barrier-serialization gaps. VGPR cap 170: bb loaded in two
// halves of 4 (peak live acc128 + a16 + bb16 + addr ~ 168).
__global__ __launch_bounds__(256,3) void gemm_qkv_kernel(
    const u16* __restrict__ A,       // h_t  [16][1024][512]
    const u16* __restrict__ B,       // wq_bf [1536][512]
    const float* __restrict__ bias,  // qkv_b [1536] f32
    u16* __restrict__ qk_t, u16* __restrict__ v_ws)
{
  __shared__ u16 smem[24576];    // 49,152 B: 2 x (A 4096 + B 8192 u16)
  const int tid = threadIdx.x, w = tid>>6, lane = tid&63, col = lane&15, quad = lane>>4;
  const int m0 = blockIdx.y*128;       // n
  const int n0 = blockIdx.x*256;       // o
  const int b  = blockIdx.z;
  const int lr = lane>>2;
  const int gsw = ((lane&3) ^ (lr&3))*8;
  const u16* Ag = A + ((size_t)b*1024 + m0 + w*32 + lr)*512 + gsw;
  const u16* Bg = B + (size_t)(n0 + w*64 + lr)*512 + gsw;
  const int mw = (w&1)*64, nw = (w>>1)*128;
  const int fsw = (quad ^ (col&3))*8;

  v4f acc[4][8];
  #pragma unroll
  for (int i=0;i<4;++i)
    #pragma unroll
    for (int j=0;j<8;++j) acc[i][j] = v4zero();

  {
    u16* Ab = smem + (w*32)*32;
    u16* Bb = smem + 4096 + (w*64)*32;
    #pragma unroll
    for (int p = 0; p < 2; ++p) gl_lds16(Ag + (size_t)(p*16)*512, Ab + p*512);
    #pragma unroll
    for (int p = 0; p < 4; ++p) gl_lds16(Bg + (size_t)(p*16)*512, Bb + p*512);
  }

  for (int kt = 0; kt < 16; ++kt){
    __syncthreads();
    if (kt < 15){
      u16* Ab = smem + ((kt+1)&1)*12288 + (w*32)*32;
      u16* Bb = smem + ((kt+1)&1)*12288 + 4096 + (w*64)*32;
      int ko = (kt+1)*32;
      #pragma unroll
      for (int p = 0; p < 2; ++p) gl_lds16(Ag + (size_t)(p*16)*512 + ko, Ab + p*512);
      #pragma unroll
      for (int p = 0; p < 4; ++p) gl_lds16(Bg + (size_t)(p*16)*512 + ko, Bb + p*512);
    }
    const u16* As = smem + (kt&1)*12288;
    const u16* Bs = As + 4096;
    v8bf a[4];
    #pragma unroll
    for (int i = 0; i < 4; ++i) a[i] = *(const v8bf*)(As + (mw+i*16+col)*32 + fsw);
    #pragma unroll
    for (int h2 = 0; h2 < 2; ++h2){
      v8bf bb[4];
      #pragma unroll
      for (int j = 0; j < 4; ++j) bb[j] = *(const v8bf*)(Bs + (nw+(h2*4+j)*16+col)*32 + fsw);
      #pragma unroll
      for (int i = 0; i < 4; ++i)
        #pragma unroll
        for (int j = 0; j < 4; ++j)
          acc[i][h2*4+j] = MFMA16(a[i], bb[j], acc[i][h2*4+j]);
    }
  }
  __syncthreads();

  float bc[8];
  #pragma unroll
  for (int j = 0; j < 8; ++j)
    bc[j] = bias[n0 + nw + j*16 + col];

  if (n0 < 1024){
    u16* Cs = smem + w*(64*72);
    #pragma unroll
    for (int half = 0; half < 2; ++half){
      #pragma unroll
      for (int i = 0; i < 4; ++i)
        #pragma unroll
        for (int jj = 0; jj < 4; ++jj)
          #pragma unroll
          for (int r = 0; r < 4; ++r)
            Cs[(i*16+quad*4+r)*72 + jj*16+col] = f2bf(acc[i][half*4+jj][r] + bc[half*4+jj]);
      u16* dst = qk_t + (size_t)b*1024*1024;
      #pragma unroll
      for (int p = 0; p < 8; ++p){
        int rl = p*8 + (lane>>3), cl = (lane&7)*8;
        *(int4*)(dst + (size_t)(m0+mw+rl)*1024 + n0+nw+half*64+cl) = *(int4*)(Cs + rl*72 + cl);
      }
    }
  } else {
    u16* Ct = smem + w*(64*80);
    #pragma unroll
    for (int half = 0; half < 2; ++half){
      #pragma unroll
      for (int i = 0; i < 4; ++i)
        #pragma unroll
        for (int jj = 0; jj < 4; ++jj)
          #pragma unroll
          for (int r = 0; r < 4; ++r)
            Ct[(jj*16+col)*80 + i*16+quad*4+r] = f2bf(acc[i][half*4+jj][r] + bc[half*4+jj]);
      u16* dst = v_ws + (size_t)b*512*1024;
      #pragma unroll
      for (int p = 0; p < 8; ++p){
        int rl = p*8 + (lane>>3), cl = (lane&7)*8;
        *(int4*)(dst + (size_t)(n0-1024 + nw + half*64 + rl)*1024 + m0+mw+cl) = *(int4*)(Ct + rl*80 + cl);
      }
    }
  }
}

// ============ Generic bf16 GEMM (proj): dbuf BK=64, 1 barrier/iter ============
__global__ __launch_bounds__(256,2) void gemm_bt_kernel(
    const u16* __restrict__ A, long long sA,
    const u16* __restrict__ B, long long sB,
    u16* __restrict__ Cbf, float* __restrict__ Cf, long long sC,
    const float* __restrict__ bias_row,
    const float* __restrict__ bias_col,
    const float* __restrict__ residf, long long sR,
    int M, int N, int K)
{
  __shared__ u16 smem[32768];   // 65,536 B: 2 x (A 8192 + B 8192 u16)
  const int tid = threadIdx.x, w = tid>>6, lane = tid&63, col = lane&15, quad = lane>>4;
  const int m0 = blockIdx.y*128, n0 = blockIdx.x*128;
  const int lr8 = lane>>3;
  const int gsw = ((lane&7) ^ lr8)*8;
  const u16* Ag = A + (size_t)blockIdx.z*sA + (size_t)(m0 + w*32 + lr8)*K + gsw;
  const u16* Bg = B + (size_t)blockIdx.z*sB + (size_t)(n0 + w*32 + lr8)*K + gsw;
  const int mw = (w&1)*64, nw = (w>>1)*64;
  const int csw = col&7;
  const int nt = K >> 6;

  v4f acc[4][4];
  #pragma unroll
  for (int i=0;i<4;++i)
    #pragma unroll
    for (int j=0;j<4;++j) acc[i][j] = v4zero();

  {
    u16* Ab = smem + (w*32)*64;
    u16* Bb = smem + 8192 + (w*32)*64;
    #pragma unroll
    for (int p = 0; p < 4; ++p){
      gl_lds16(Ag + (size_t)(p*8)*K, Ab + p*512);
      gl_lds16(Bg + (size_t)(p*8)*K, Bb + p*512);
    }
  }

  for (int kt = 0; kt < nt; ++kt){
    __syncthreads();
    if (kt+1 < nt){
      u16* Ab = smem + ((kt+1)&1)*16384 + (w*32)*64;
      u16* Bb = smem + ((kt+1)&1)*16384 + 8192 + (w*32)*64;
      int ko = (kt+1)*64;
      #pragma unroll
      for (int p = 0; p < 4; ++p){
        gl_lds16(Ag + (size_t)(p*8)*K + ko, Ab + p*512);
        gl_lds16(Bg + (size_t)(p*8)*K + ko, Bb + p*512);
      }
    }
    const u16* As = smem + (kt&1)*16384;
    const u16* Bs = As + 8192;
    #pragma unroll
    for (int kh = 0; kh < 2; ++kh){
      const int fs = ((kh*4 + quad) ^ csw)*8;
      v8bf a[4], bb[4];
      #pragma unroll
      for (int i = 0; i < 4; ++i) a[i]  = *(const v8bf*)(As + (mw+i*16+col)*64 + fs);
      #pragma unroll
      for (int j = 0; j < 4; ++j) bb[j] = *(const v8bf*)(Bs + (nw+j*16+col)*64 + fs);
      #pragma unroll
      for (int i = 0; i < 4; ++i)
        #pragma unroll
        for (int j = 0; j < 4; ++j)
          acc[i][j] = MFMA16(a[i], bb[j], acc[i][j]);
    }
  }
  __syncthreads();

  float br[4][4], bc[4];
  #pragma unroll
  for (int i = 0; i < 4; ++i)
    #pragma unroll
    for (int r = 0; r < 4; ++r)
      br[i][r] = bias_row ? bias_row[m0+mw+i*16+quad*4+r] : 0.f;
  #pragma unroll
  for (int j = 0; j < 4; ++j)
    bc[j] = bias_col ? bias_col[n0+nw+j*16+col] : 0.f;

  if (Cf){
    float* Cb = Cf + (size_t)blockIdx.z*sC;
    const float* Rb = residf ? residf + (size_t)blockIdx.z*sR : nullptr;
    #pragma unroll
    for (int i = 0; i < 4; ++i)
      #pragma unroll
      for (int r = 0; r < 4; ++r){
        int row = m0+mw+i*16+quad*4+r;
        #pragma unroll
        for (int j = 0; j < 4; ++j){
          size_t goff = (size_t)row*N + n0+nw+j*16+col;
          float val = acc[i][j][r] + br[i][r] + bc[j];
          if (Rb) val += Rb[goff];
          Cb[goff] = val;
        }
      }
  } else {
    u16* Cs = smem + w*(64*72);
    #pragma unroll
    for (int i = 0; i < 4; ++i)
      #pragma unroll
      for (int j = 0; j < 4; ++j)
        #pragma unroll
        for (int r = 0; r < 4; ++r)
          Cs[(i*16+quad*4+r)*72 + j*16+col] = f2bf(acc[i][j][r] + br[i][r] + bc[j]);
    __syncthreads();
    u16* Cb = Cbf + (size_t)blockIdx.z*sC;
    #pragma unroll
    for (int p = 0; p < 8; ++p){
      int rl = p*8 + (lane>>3), cl = (lane&7)*8;
      size_t goff = (size_t)(m0+mw+rl)*N + n0+nw+cl;
      *(int4*)(Cb + goff) = *(int4*)(Cs + rl*72 + cl);
    }
  }
}

// ============ Fused flash attention: R4 structure + 4-chain QK accumulators ============
// qk[b][n][0..511]=q, [512..1023]=k; vv[b][c_all][m]; out[b][n][c_all]
// flat grid 512 x 256: qt=id>>6, bh=id&63. 2 blocks/CU (grid-limited).
// B1 -> V-pf(t+1) -> QK(t) -> B2 -> K-pf(t+1) -> exp/pack -> PV(t).
// QK accumulators split by k-parity (s0a/s0b, s1a/s1b): 4 independent MFMA32 chains of
// depth 4 instead of 2 chains of depth 8 -- hides MFMA dependent-use latency at the
// 2-waves/SIMD occupancy this grid allows. Merged (32 VALU adds) before exp.
// In-register softmax via swapped QK^T (T12: cvt_pk + permlane32_swap), no P buffer.
__global__ __launch_bounds__(256,2) void attn_kernel(const u16* __restrict__ qk, const u16* __restrict__ vv,
                                                     u16* __restrict__ outp){
  __shared__ u16 smem[24576];        // 48KB: Ks [64][128] (16KB) + Vs 2x[128][64] (32KB)
  u16* Ks = smem;                    // single buffer
  u16* Vs = smem + 8192;             // double buffer
  const int id = blockIdx.x;
  const int qt = id >> 6, bh = id & 63, b = bh >> 2, h = bh & 3;
  const int n0 = qt*128;
  const int tid = threadIdx.x, w = tid>>6, lane = tid&63;
  const int nl = lane & 31, hi = lane >> 5;
  const int key = nl & 7;
  const size_t bq = (size_t)b*1024*1024;
  const float scale2 = 0.12751742f;  // (1/sqrt(128)) * log2(e)

  // Q as B-operand fragments in registers: col n = n0+w*32+nl, k granule kk*2+hi
  v8bf qf[8];
  {
    const u16* qbase = qk + bq + (size_t)(n0 + w*32 + nl)*1024 + h*128 + hi*8;
    #pragma unroll
    for (int kk = 0; kk < 8; ++kk)
      qf[kk] = *(const v8bf*)(qbase + kk*16);
  }

  v16f o[4];
  #pragma unroll
  for (int j=0;j<4;++j)
    #pragma unroll
    for (int r=0;r<16;++r) o[j][r] = 0.f;
  float ls0 = 0.f, ls1 = 0.f;

  // staging lane constants (swizzle folded into global source granule)
  const int krow = w*4 + (lane>>4);
  const int kgr  = (lane&15) ^ (krow&7);
  const u16* kg_base = qk + bq + (size_t)krow*1024 + 512 + h*128 + kgr*8;
  const int vrow = w*8 + (lane>>3);
  const int vgr  = (lane&7) ^ (vrow&7);
  const u16* vg_base = vv + ((size_t)b*512 + h*128 + vrow)*1024 + vgr*8;

  // prologue: stage K(0) and V(0)
  #pragma unroll
  for (int p = 0; p < 4; ++p)
    gl_lds16(kg_base + (size_t)(p*16)*1024, Ks + (w*4)*128 + p*2048);
  #pragma unroll
  for (int p = 0; p < 4; ++p)
    gl_lds16(vg_base + (size_t)(p*32)*1024, Vs + (w*8)*64 + p*2048);

  for (int t = 0; t < 16; ++t){
    const int mt = t*64;
    __syncthreads();                       // B1: K(t) and V(t) resident

    if (t < 15){                           // V prefetch t+1 -> other buffer; drains at B2 (covered by QK)
      int mt2 = mt + 64;
      u16* vl = Vs + (((t+1)&1)<<13) + (w*8)*64;
      #pragma unroll
      for (int p = 0; p < 4; ++p)
        gl_lds16(vg_base + (size_t)(p*32)*1024 + mt2, vl + p*2048);
    }

    // S^T = K Q^T (raw), 4 independent accumulation chains (k-parity split)
    v16f s0a, s0b, s1a, s1b;
    #pragma unroll
    for (int r=0;r<16;++r){ s0a[r]=0.f; s0b[r]=0.f; s1a[r]=0.f; s1b[r]=0.f; }
    __builtin_amdgcn_s_setprio(1);
    #pragma unroll
    for (int kk = 0; kk < 8; ++kk){
      int g = (((kk*2 + hi) ^ key) << 3);
      v8bf k0 = *(const v8bf*)(Ks + (nl<<7) + g);
      v8bf k1 = *(const v8bf*)(Ks + ((32+nl)<<7) + g);
      if (kk & 1){
        s0b = MFMA32(k0, qf[kk], s0b);
        s1b = MFMA32(k1, qf[kk], s1b);
      } else {
        s0a = MFMA32(k0, qf[kk], s0a);
        s1a = MFMA32(k1, qf[kk], s1a);
      }
    }
    __builtin_amdgcn_s_setprio(0);

    __syncthreads();                       // B2: all waves consumed K(t); Ks free

    if (t < 15){                           // K prefetch t+1 -> Ks; drains at B1' (covered by exp+PV)
      int mt2 = mt + 64;
      #pragma unroll
      for (int p = 0; p < 4; ++p)
        gl_lds16(kg_base + (size_t)(mt2 + p*16)*1024, Ks + (w*4)*128 + p*2048);
    }

    // merge chains, p = exp2(s*scale2), 2 independent lane-local sum chains
    v16f s0, s1;
    #pragma unroll
    for (int r = 0; r < 16; ++r){
      s0[r] = __builtin_amdgcn_exp2f((s0a[r] + s0b[r])*scale2);
      s1[r] = __builtin_amdgcn_exp2f((s1a[r] + s1b[r])*scale2);
      ls0 += s0[r];
      ls1 += s1[r];
    }

    // O += P V^T, P packed to A-frags in-register (cvt_pk + permlane32_swap)
    const u16* Vc = Vs + ((t&1)<<13);
    #pragma unroll
    for (int half = 0; half < 2; ++half){
      const v16f& ps = half ? s1 : s0;
      #pragma unroll
      for (int sel = 0; sel < 2; ++sel){
        const int sb = sel*8;
        unsigned int pA = pkbf(ps[sb+0], ps[sb+1]);
        unsigned int pB = pkbf(ps[sb+2], ps[sb+3]);
        unsigned int pC = pkbf(ps[sb+4], ps[sb+5]);
        unsigned int pD = pkbf(ps[sb+6], ps[sb+7]);
        asm("v_permlane32_swap_b32 %0, %1" : "+v"(pA), "+v"(pC));
        asm("v_permlane32_swap_b32 %0, %1" : "+v"(pB), "+v"(pD));
        union { v8bf v; unsigned int u[4]; } pa;
        pa.u[0] = pA; pa.u[1] = pB; pa.u[2] = pC; pa.u[3] = pD;
        const int kkv = half*2 + sel;
        const int gv = (((kkv*2 + hi) ^ key) << 3);
        __builtin_amdgcn_s_setprio(1);
        #pragma unroll
        for (int j = 0; j < 4; ++j){
          v8bf bv = *(const v8bf*)(Vc + ((j*32 + nl)<<6) + gv);
          o[j] = MFMA32(pa.v, bv, o[j]);
        }
        __builtin_amdgcn_s_setprio(0);
      }
    }
  }
  __syncthreads();

  // full row-sum for q-row nl (other half of m lives in lane^32), then redistribute
  // 1/l to the 32x32 C/D row layout: row(reg) = (reg&3) + 8*(reg>>2) + 4*hi
  float lsum = ls0 + ls1;
  lsum += __shfl_xor(lsum, 32);
  float invl[16];
  #pragma unroll
  for (int r = 0; r < 16; ++r){
    int nr = (r&3) + 8*(r>>2) + 4*hi;
    invl[r] = 1.f / __shfl(lsum, nr);
  }

  // bounce O through LDS (swizzled [128][128]) for coalesced 16B stores
  #pragma unroll
  for (int j = 0; j < 4; ++j)
    #pragma unroll
    for (int r = 0; r < 16; ++r){
      int rr = w*32 + (r&3) + 8*(r>>2) + 4*hi;
      int c  = j*32 + nl;
      smem[(rr<<7) + ((((c>>3) ^ (rr&7))<<3)) + (c&7)] = f2bf(o[j][r] * invl[r]);
    }
  __syncthreads();
  #pragma unroll
  for (int p = 0; p < 8; ++p){
    int nr = p*16 + (tid>>4);
    int gc = (tid&15) ^ (nr&7);
    *(int4*)(outp + ((size_t)b*1024 + n0 + nr)*512 + h*128 + ((tid&15)<<3)) =
      *(int4*)(smem + (nr<<7) + (gc<<3));
  }
}

extern "C" void kernel_launch(void* const* d_in, const int* in_sizes, int n_in,
                              void* d_out, int out_size, void* d_ws, size_t ws_size,
                              hipStream_t stream){
  const float* x      = (const float*)d_in[0];
  const float* norm_w = (const float*)d_in[1];
  const float* norm_b = (const float*)d_in[2];
  const float* qkv_w  = (const float*)d_in[3];
  const float* qkv_b  = (const float*)d_in[4];
  const float* proj_w = (const float*)d_in[5];
  const float* proj_b = (const float*)d_in[6];
  float* out = (float*)d_out;

  u16* h_t   = (u16*)d_ws;                                  // [16][1024][512]
  u16* qk_t  = h_t  + (size_t)16*1024*512;                  // [16][1024][1024]
  u16* v_ws  = qk_t + (size_t)16*1024*1024;                 // [16][512][1024]
  u16* wq_bf = v_ws + (size_t)16*512*1024;                  // [1536][512]
  u16* wp_bf = wq_bf + (size_t)1536*512;                    // [512][512]
  u16* attnout = h_t;                                       // reuse

  cvt2_kernel<<<1024, 256, 0, stream>>>(qkv_w, wq_bf, 1536*512, proj_w, wp_bf, 512*512);
  gn_fused_kernel<<<512, 256, 0, stream>>>(x, norm_w, norm_b, h_t);

  gemm_qkv_kernel<<<dim3(6,8,16), 256, 0, stream>>>(h_t, wq_bf, qkv_b, qk_t, v_ws);

  attn_kernel<<<512, 256, 0, stream>>>(qk_t, v_ws, attnout);

  gemm_bt_kernel<<<dim3(8,4,16), 256, 0, stream>>>(
      wp_bf, 0, attnout, (long long)1024*512,
      nullptr, out, (long long)512*1024, proj_b, nullptr, x, (long long)512*1024, 512, 1024, 512);
}

// Round 10
// 204.544 us; speedup vs baseline: 1.0275x; 1.0275x over previous
//
#include <hip/hip_runtime.h>

typedef __bf16 v8bf __attribute__((ext_vector_type(8)));
typedef float  v4f  __attribute__((ext_vector_type(4)));
typedef float  v16f __attribute__((ext_vector_type(16)));
typedef unsigned short u16;

__device__ __forceinline__ u16 f2bf(float f){
  __bf16 h = (__bf16)f;
  union { __bf16 h; u16 u; } c; c.h = h; return c.u;
}
__device__ __forceinline__ v4f v4zero(){ v4f z; z[0]=0.f; z[1]=0.f; z[2]=0.f; z[3]=0.f; return z; }

#define MFMA16(a,b,c) __builtin_amdgcn_mfma_f32_16x16x32_bf16((a),(b),(c),0,0,0)
#define MFMA32(a,b,c) __builtin_amdgcn_mfma_f32_32x32x16_bf16((a),(b),(c),0,0,0)

// async global->LDS, 16B per lane; LDS dest = wave-uniform base + lane*16
__device__ __forceinline__ void gl_lds16(const u16* g, u16* l){
  __builtin_amdgcn_global_load_lds((const __attribute__((address_space(1))) void*)g,
                                   (__attribute__((address_space(3))) void*)l, 16, 0, 0);
}

// v_cvt_pk_bf16_f32: pack two f32 -> one u32 of 2 bf16 (no builtin on gfx950)
__device__ __forceinline__ unsigned int pkbf(float lo, float hi){
  unsigned int r;
  asm("v_cvt_pk_bf16_f32 %0, %1, %2" : "=v"(r) : "v"(lo), "v"(hi));
  return r;
}

// ============ Merged: GroupNorm (blocks 0..511) + f32->bf16 weight convert (blocks 512..1535) ============
// Saves one kernel launch + its serial gap; cvt work (~7MB) rides along with the
// memory-bound gn (~80MB) since the two touch disjoint tensors.
__global__ __launch_bounds__(256) void pre_kernel(
    const float* __restrict__ x, const float* __restrict__ nw, const float* __restrict__ nbv,
    u16* __restrict__ h_t,
    const float* __restrict__ wa, u16* __restrict__ da, int na,
    const float* __restrict__ wb, u16* __restrict__ db, int nbn)
{
  __shared__ float xs[16*1028 + 16];
  const int bid = blockIdx.x;
  const int tid = threadIdx.x;

  if (bid >= 512){                      // ---- weight convert branch ----
    int i = ((bid - 512)*256 + tid)*4;
    const float* s; u16* d; int off;
    if (i < na){ s = wa; d = da; off = i; }
    else { off = i - na; if (off >= nbn) return; s = wb; d = db; }
    float4 v = *(const float4*)(s + off);
    ushort4 o;
    o.x = f2bf(v.x); o.y = f2bf(v.y); o.z = f2bf(v.z); o.w = f2bf(v.w);
    *(ushort4*)(d + off) = o;
    return;
  }

  // ---- GroupNorm: stats + apply + transpose ----
  const int b = bid >> 5, g = bid & 31, c0 = g*16;
  const float* base = x + (size_t)(b*512 + c0)*1024;

  float s = 0.f, ss = 0.f;
  #pragma unroll
  for (int it = 0; it < 16; ++it){
    float4 v = *(const float4*)(base + it*1024 + tid*4);
    s  += v.x + v.y + v.z + v.w;
    ss += v.x*v.x + v.y*v.y + v.z*v.z + v.w*v.w;
    *(float4*)(xs + it*1028 + tid*4) = v;
  }
  #pragma unroll
  for (int off = 32; off > 0; off >>= 1){ s += __shfl_down(s, off); ss += __shfl_down(ss, off); }
  float* red = xs + 16*1028;
  int w = tid >> 6;
  if ((tid & 63) == 0){ red[w] = s; red[4+w] = ss; }
  __syncthreads();
  if (tid == 0){
    float S  = red[0]+red[1]+red[2]+red[3];
    float SS = red[4]+red[5]+red[6]+red[7];
    float mean = S * (1.f/16384.f);
    float var  = SS * (1.f/16384.f) - mean*mean;
    red[8] = mean;
    red[9] = rsqrtf(var + 1e-5f);
  }
  __syncthreads();
  const float mean = red[8], rstd = red[9];

  const int half = tid & 1, nbase = tid >> 1;
  float wv[8], bv[8];
  #pragma unroll
  for (int cl = 0; cl < 8; ++cl){
    int c = c0 + half*8 + cl;
    wv[cl] = nw[c] * rstd;
    bv[cl] = nbv[c] - mean * wv[cl];
  }
  #pragma unroll
  for (int p = 0; p < 8; ++p){
    int n = nbase + p*128;
    alignas(16) u16 tmp[8];
    #pragma unroll
    for (int cl = 0; cl < 8; ++cl)
      tmp[cl] = f2bf(xs[(half*8 + cl)*1028 + n] * wv[cl] + bv[cl]);
    *(int4*)(h_t + ((size_t)b*1024 + n)*512 + c0 + half*8) = *(int4*)tmp;
  }
}

// ============ Fused QKV GEMM, double-buffered BK=32, 1 barrier/iter, 3 blocks/CU ============
// 768 blocks: with (256,2) residency was 1.5 occupancy rounds (256-block tail at half
// machine). LDS 48KB fits 3/CU (144KB <= 160KB); (256,3) -> exactly one round, and a
// 3rd drifting block fills barrier-serialization gaps. VGPR cap 170: bb loaded in two
// halves of 4 (peak live acc128 + a16 + bb16 + addr ~ 168).
__global__ __launch_bounds__(256,3) void gemm_qkv_kernel(
    const u16* __restrict__ A,       // h_t  [16][1024][512]
    const u16* __restrict__ B,       // wq_bf [1536][512]
    const float* __restrict__ bias,  // qkv_b [1536] f32
    u16* __restrict__ qk_t, u16* __restrict__ v_ws)
{
  __shared__ u16 smem[24576];    // 49,152 B: 2 x (A 4096 + B 8192 u16)
  const int tid = threadIdx.x, w = tid>>6, lane = tid&63, col = lane&15, quad = lane>>4;
  const int m0 = blockIdx.y*128;       // n
  const int n0 = blockIdx.x*256;       // o
  const int b  = blockIdx.z;
  const int lr = lane>>2;
  const int gsw = ((lane&3) ^ (lr&3))*8;
  const u16* Ag = A + ((size_t)b*1024 + m0 + w*32 + lr)*512 + gsw;
  const u16* Bg = B + (size_t)(n0 + w*64 + lr)*512 + gsw;
  const int mw = (w&1)*64, nw = (w>>1)*128;
  const int fsw = (quad ^ (col&3))*8;

  v4f acc[4][8];
  #pragma unroll
  for (int i=0;i<4;++i)
    #pragma unroll
    for (int j=0;j<8;++j) acc[i][j] = v4zero();

  {
    u16* Ab = smem + (w*32)*32;
    u16* Bb = smem + 4096 + (w*64)*32;
    #pragma unroll
    for (int p = 0; p < 2; ++p) gl_lds16(Ag + (size_t)(p*16)*512, Ab + p*512);
    #pragma unroll
    for (int p = 0; p < 4; ++p) gl_lds16(Bg + (size_t)(p*16)*512, Bb + p*512);
  }

  for (int kt = 0; kt < 16; ++kt){
    __syncthreads();
    if (kt < 15){
      u16* Ab = smem + ((kt+1)&1)*12288 + (w*32)*32;
      u16* Bb = smem + ((kt+1)&1)*12288 + 4096 + (w*64)*32;
      int ko = (kt+1)*32;
      #pragma unroll
      for (int p = 0; p < 2; ++p) gl_lds16(Ag + (size_t)(p*16)*512 + ko, Ab + p*512);
      #pragma unroll
      for (int p = 0; p < 4; ++p) gl_lds16(Bg + (size_t)(p*16)*512 + ko, Bb + p*512);
    }
    const u16* As = smem + (kt&1)*12288;
    const u16* Bs = As + 4096;
    v8bf a[4];
    #pragma unroll
    for (int i = 0; i < 4; ++i) a[i] = *(const v8bf*)(As + (mw+i*16+col)*32 + fsw);
    #pragma unroll
    for (int h2 = 0; h2 < 2; ++h2){
      v8bf bb[4];
      #pragma unroll
      for (int j = 0; j < 4; ++j) bb[j] = *(const v8bf*)(Bs + (nw+(h2*4+j)*16+col)*32 + fsw);
      #pragma unroll
      for (int i = 0; i < 4; ++i)
        #pragma unroll
        for (int j = 0; j < 4; ++j)
          acc[i][h2*4+j] = MFMA16(a[i], bb[j], acc[i][h2*4+j]);
    }
  }
  __syncthreads();

  float bc[8];
  #pragma unroll
  for (int j = 0; j < 8; ++j)
    bc[j] = bias[n0 + nw + j*16 + col];

  if (n0 < 1024){
    u16* Cs = smem + w*(64*72);
    #pragma unroll
    for (int half = 0; half < 2; ++half){
      #pragma unroll
      for (int i = 0; i < 4; ++i)
        #pragma unroll
        for (int jj = 0; jj < 4; ++jj)
          #pragma unroll
          for (int r = 0; r < 4; ++r)
            Cs[(i*16+quad*4+r)*72 + jj*16+col] = f2bf(acc[i][half*4+jj][r] + bc[half*4+jj]);
      u16* dst = qk_t + (size_t)b*1024*1024;
      #pragma unroll
      for (int p = 0; p < 8; ++p){
        int rl = p*8 + (lane>>3), cl = (lane&7)*8;
        *(int4*)(dst + (size_t)(m0+mw+rl)*1024 + n0+nw+half*64+cl) = *(int4*)(Cs + rl*72 + cl);
      }
    }
  } else {
    u16* Ct = smem + w*(64*80);
    #pragma unroll
    for (int half = 0; half < 2; ++half){
      #pragma unroll
      for (int i = 0; i < 4; ++i)
        #pragma unroll
        for (int jj = 0; jj < 4; ++jj)
          #pragma unroll
          for (int r = 0; r < 4; ++r)
            Ct[(jj*16+col)*80 + i*16+quad*4+r] = f2bf(acc[i][half*4+jj][r] + bc[half*4+jj]);
      u16* dst = v_ws + (size_t)b*512*1024;
      #pragma unroll
      for (int p = 0; p < 8; ++p){
        int rl = p*8 + (lane>>3), cl = (lane&7)*8;
        *(int4*)(dst + (size_t)(n0-1024 + nw + half*64 + rl)*1024 + m0+mw+cl) = *(int4*)(Ct + rl*80 + cl);
      }
    }
  }
}

// ============ Generic bf16 GEMM (proj): dbuf BK=64, 1 barrier/iter ============
__global__ __launch_bounds__(256,2) void gemm_bt_kernel(
    const u16* __restrict__ A, long long sA,
    const u16* __restrict__ B, long long sB,
    u16* __restrict__ Cbf, float* __restrict__ Cf, long long sC,
    const float* __restrict__ bias_row,
    const float* __restrict__ bias_col,
    const float* __restrict__ residf, long long sR,
    int M, int N, int K)
{
  __shared__ u16 smem[32768];   // 65,536 B: 2 x (A 8192 + B 8192 u16)
  const int tid = threadIdx.x, w = tid>>6, lane = tid&63, col = lane&15, quad = lane>>4;
  const int m0 = blockIdx.y*128, n0 = blockIdx.x*128;
  const int lr8 = lane>>3;
  const int gsw = ((lane&7) ^ lr8)*8;
  const u16* Ag = A + (size_t)blockIdx.z*sA + (size_t)(m0 + w*32 + lr8)*K + gsw;
  const u16* Bg = B + (size_t)blockIdx.z*sB + (size_t)(n0 + w*32 + lr8)*K + gsw;
  const int mw = (w&1)*64, nw = (w>>1)*64;
  const int csw = col&7;
  const int nt = K >> 6;

  v4f acc[4][4];
  #pragma unroll
  for (int i=0;i<4;++i)
    #pragma unroll
    for (int j=0;j<4;++j) acc[i][j] = v4zero();

  {
    u16* Ab = smem + (w*32)*64;
    u16* Bb = smem + 8192 + (w*32)*64;
    #pragma unroll
    for (int p = 0; p < 4; ++p){
      gl_lds16(Ag + (size_t)(p*8)*K, Ab + p*512);
      gl_lds16(Bg + (size_t)(p*8)*K, Bb + p*512);
    }
  }

  for (int kt = 0; kt < nt; ++kt){
    __syncthreads();
    if (kt+1 < nt){
      u16* Ab = smem + ((kt+1)&1)*16384 + (w*32)*64;
      u16* Bb = smem + ((kt+1)&1)*16384 + 8192 + (w*32)*64;
      int ko = (kt+1)*64;
      #pragma unroll
      for (int p = 0; p < 4; ++p){
        gl_lds16(Ag + (size_t)(p*8)*K + ko, Ab + p*512);
        gl_lds16(Bg + (size_t)(p*8)*K + ko, Bb + p*512);
      }
    }
    const u16* As = smem + (kt&1)*16384;
    const u16* Bs = As + 8192;
    #pragma unroll
    for (int kh = 0; kh < 2; ++kh){
      const int fs = ((kh*4 + quad) ^ csw)*8;
      v8bf a[4], bb[4];
      #pragma unroll
      for (int i = 0; i < 4; ++i) a[i]  = *(const v8bf*)(As + (mw+i*16+col)*64 + fs);
      #pragma unroll
      for (int j = 0; j < 4; ++j) bb[j] = *(const v8bf*)(Bs + (nw+j*16+col)*64 + fs);
      #pragma unroll
      for (int i = 0; i < 4; ++i)
        #pragma unroll
        for (int j = 0; j < 4; ++j)
          acc[i][j] = MFMA16(a[i], bb[j], acc[i][j]);
    }
  }
  __syncthreads();

  float br[4][4], bc[4];
  #pragma unroll
  for (int i = 0; i < 4; ++i)
    #pragma unroll
    for (int r = 0; r < 4; ++r)
      br[i][r] = bias_row ? bias_row[m0+mw+i*16+quad*4+r] : 0.f;
  #pragma unroll
  for (int j = 0; j < 4; ++j)
    bc[j] = bias_col ? bias_col[n0+nw+j*16+col] : 0.f;

  if (Cf){
    float* Cb = Cf + (size_t)blockIdx.z*sC;
    const float* Rb = residf ? residf + (size_t)blockIdx.z*sR : nullptr;
    #pragma unroll
    for (int i = 0; i < 4; ++i)
      #pragma unroll
      for (int r = 0; r < 4; ++r){
        int row = m0+mw+i*16+quad*4+r;
        #pragma unroll
        for (int j = 0; j < 4; ++j){
          size_t goff = (size_t)row*N + n0+nw+j*16+col;
          float val = acc[i][j][r] + br[i][r] + bc[j];
          if (Rb) val += Rb[goff];
          Cb[goff] = val;
        }
      }
  } else {
    u16* Cs = smem + w*(64*72);
    #pragma unroll
    for (int i = 0; i < 4; ++i)
      #pragma unroll
      for (int j = 0; j < 4; ++j)
        #pragma unroll
        for (int r = 0; r < 4; ++r)
          Cs[(i*16+quad*4+r)*72 + j*16+col] = f2bf(acc[i][j][r] + br[i][r] + bc[j]);
    __syncthreads();
    u16* Cb = Cbf + (size_t)blockIdx.z*sC;
    #pragma unroll
    for (int p = 0; p < 8; ++p){
      int rl = p*8 + (lane>>3), cl = (lane&7)*8;
      size_t goff = (size_t)(m0+mw+rl)*N + n0+nw+cl;
      *(int4*)(Cb + goff) = *(int4*)(Cs + rl*72 + cl);
    }
  }
}

// ============ Fused flash attention: R4 structure + 4-chain QK + V reg-preload PV ============
// qk[b][n][0..511]=q, [512..1023]=k; vv[b][c_all][m]; out[b][n][c_all]
// flat grid 512 x 256: qt=id>>6, bh=id&63. 2 blocks/CU (grid-limited).
// B1 -> V-pf(t+1) -> QK(t) -> B2 -> K-pf(t+1) -> V(t) LDS->reg preload -> exp/pack -> PV(t).
// V fragments are preloaded to registers overlapping the exp/pack VALU phase, so the
// PV cluster issues 16 reg-only MFMA32s with no lgkm waits. VGPR ~176 is free: occupancy
// is block-count-limited at 2/CU (needs 2 waves/SIMD <= 512/176).
// In-register softmax via swapped QK^T (T12: cvt_pk + permlane32_swap), no P buffer.
__global__ __launch_bounds__(256,2) void attn_kernel(const u16* __restrict__ qk, const u16* __restrict__ vv,
                                                     u16* __restrict__ outp){
  __shared__ u16 smem[24576];        // 48KB: Ks [64][128] (16KB) + Vs 2x[128][64] (32KB)
  u16* Ks = smem;                    // single buffer
  u16* Vs = smem + 8192;             // double buffer
  const int id = blockIdx.x;
  const int qt = id >> 6, bh = id & 63, b = bh >> 2, h = bh & 3;
  const int n0 = qt*128;
  const int tid = threadIdx.x, w = tid>>6, lane = tid&63;
  const int nl = lane & 31, hi = lane >> 5;
  const int key = nl & 7;
  const size_t bq = (size_t)b*1024*1024;
  const float scale2 = 0.12751742f;  // (1/sqrt(128)) * log2(e)

  // Q as B-operand fragments in registers: col n = n0+w*32+nl, k granule kk*2+hi
  v8bf qf[8];
  {
    const u16* qbase = qk + bq + (size_t)(n0 + w*32 + nl)*1024 + h*128 + hi*8;
    #pragma unroll
    for (int kk = 0; kk < 8; ++kk)
      qf[kk] = *(const v8bf*)(qbase + kk*16);
  }

  v16f o[4];
  #pragma unroll
  for (int j=0;j<4;++j)
    #pragma unroll
    for (int r=0;r<16;++r) o[j][r] = 0.f;
  float ls0 = 0.f, ls1 = 0.f;

  // staging lane constants (swizzle folded into global source granule)
  const int krow = w*4 + (lane>>4);
  const int kgr  = (lane&15) ^ (krow&7);
  const u16* kg_base = qk + bq + (size_t)krow*1024 + 512 + h*128 + kgr*8;
  const int vrow = w*8 + (lane>>3);
  const int vgr  = (lane&7) ^ (vrow&7);
  const u16* vg_base = vv + ((size_t)b*512 + h*128 + vrow)*1024 + vgr*8;

  // prologue: stage K(0) and V(0)
  #pragma unroll
  for (int p = 0; p < 4; ++p)
    gl_lds16(kg_base + (size_t)(p*16)*1024, Ks + (w*4)*128 + p*2048);
  #pragma unroll
  for (int p = 0; p < 4; ++p)
    gl_lds16(vg_base + (size_t)(p*32)*1024, Vs + (w*8)*64 + p*2048);

  for (int t = 0; t < 16; ++t){
    const int mt = t*64;
    __syncthreads();                       // B1: K(t) and V(t) resident

    if (t < 15){                           // V prefetch t+1 -> other buffer; drains at B2 (covered by QK)
      int mt2 = mt + 64;
      u16* vl = Vs + (((t+1)&1)<<13) + (w*8)*64;
      #pragma unroll
      for (int p = 0; p < 4; ++p)
        gl_lds16(vg_base + (size_t)(p*32)*1024 + mt2, vl + p*2048);
    }

    // S^T = K Q^T (raw), 4 independent accumulation chains (k-parity split)
    v16f s0a, s0b, s1a, s1b;
    #pragma unroll
    for (int r=0;r<16;++r){ s0a[r]=0.f; s0b[r]=0.f; s1a[r]=0.f; s1b[r]=0.f; }
    __builtin_amdgcn_s_setprio(1);
    #pragma unroll
    for (int kk = 0; kk < 8; ++kk){
      int g = (((kk*2 + hi) ^ key) << 3);
      v8bf k0 = *(const v8bf*)(Ks + (nl<<7) + g);
      v8bf k1 = *(const v8bf*)(Ks + ((32+nl)<<7) + g);
      if (kk & 1){
        s0b = MFMA32(k0, qf[kk], s0b);
        s1b = MFMA32(k1, qf[kk], s1b);
      } else {
        s0a = MFMA32(k0, qf[kk], s0a);
        s1a = MFMA32(k1, qf[kk], s1a);
      }
    }
    __builtin_amdgcn_s_setprio(0);

    __syncthreads();                       // B2: all waves consumed K(t); Ks free

    if (t < 15){                           // K prefetch t+1 -> Ks; drains at B1' (covered by exp+PV)
      int mt2 = mt + 64;
      #pragma unroll
      for (int p = 0; p < 4; ++p)
        gl_lds16(kg_base + (size_t)(mt2 + p*16)*1024, Ks + (w*4)*128 + p*2048);
    }

    // preload V(t) fragments LDS->reg; latency overlaps the exp/pack VALU below.
    // Buffer (t&1) stays valid: next overwrite is iter t+1's V-prefetch (after B1').
    const u16* Vc = Vs + ((t&1)<<13);
    v8bf vr0[4], vr1[4], vr2[4], vr3[4];
    #pragma unroll
    for (int j = 0; j < 4; ++j){
      const u16* vb = Vc + ((j*32 + nl)<<6);
      vr0[j] = *(const v8bf*)(vb + (((0*2 + hi) ^ key) << 3));
      vr1[j] = *(const v8bf*)(vb + (((1*2 + hi) ^ key) << 3));
      vr2[j] = *(const v8bf*)(vb + (((2*2 + hi) ^ key) << 3));
      vr3[j] = *(const v8bf*)(vb + (((3*2 + hi) ^ key) << 3));
    }

    // merge chains, p = exp2(s*scale2), 2 independent lane-local sum chains
    v16f s0, s1;
    #pragma unroll
    for (int r = 0; r < 16; ++r){
      s0[r] = __builtin_amdgcn_exp2f((s0a[r] + s0b[r])*scale2);
      s1[r] = __builtin_amdgcn_exp2f((s1a[r] + s1b[r])*scale2);
      ls0 += s0[r];
      ls1 += s1[r];
    }

    // O += P V^T, P packed to A-frags in-register (cvt_pk + permlane32_swap); PV reg-only
    #pragma unroll
    for (int half = 0; half < 2; ++half){
      const v16f& ps = half ? s1 : s0;
      #pragma unroll
      for (int sel = 0; sel < 2; ++sel){
        const int sb = sel*8;
        unsigned int pA = pkbf(ps[sb+0], ps[sb+1]);
        unsigned int pB = pkbf(ps[sb+2], ps[sb+3]);
        unsigned int pC = pkbf(ps[sb+4], ps[sb+5]);
        unsigned int pD = pkbf(ps[sb+6], ps[sb+7]);
        asm("v_permlane32_swap_b32 %0, %1" : "+v"(pA), "+v"(pC));
        asm("v_permlane32_swap_b32 %0, %1" : "+v"(pB), "+v"(pD));
        union { v8bf v; unsigned int u[4]; } pa;
        pa.u[0] = pA; pa.u[1] = pB; pa.u[2] = pC; pa.u[3] = pD;
        const int kkv = half*2 + sel;
        __builtin_amdgcn_s_setprio(1);
        #pragma unroll
        for (int j = 0; j < 4; ++j){
          v8bf bv = (kkv == 0) ? vr0[j] : (kkv == 1) ? vr1[j] : (kkv == 2) ? vr2[j] : vr3[j];
          o[j] = MFMA32(pa.v, bv, o[j]);
        }
        __builtin_amdgcn_s_setprio(0);
      }
    }
  }
  __syncthreads();

  // full row-sum for q-row nl (other half of m lives in lane^32), then redistribute
  // 1/l to the 32x32 C/D row layout: row(reg) = (reg&3) + 8*(reg>>2) + 4*hi
  float lsum = ls0 + ls1;
  lsum += __shfl_xor(lsum, 32);
  float invl[16];
  #pragma unroll
  for (int r = 0; r < 16; ++r){
    int nr = (r&3) + 8*(r>>2) + 4*hi;
    invl[r] = 1.f / __shfl(lsum, nr);
  }

  // bounce O through LDS (swizzled [128][128]) for coalesced 16B stores
  #pragma unroll
  for (int j = 0; j < 4; ++j)
    #pragma unroll
    for (int r = 0; r < 16; ++r){
      int rr = w*32 + (r&3) + 8*(r>>2) + 4*hi;
      int c  = j*32 + nl;
      smem[(rr<<7) + ((((c>>3) ^ (rr&7))<<3)) + (c&7)] = f2bf(o[j][r] * invl[r]);
    }
  __syncthreads();
  #pragma unroll
  for (int p = 0; p < 8; ++p){
    int nr = p*16 + (tid>>4);
    int gc = (tid&15) ^ (nr&7);
    *(int4*)(outp + ((size_t)b*1024 + n0 + nr)*512 + h*128 + ((tid&15)<<3)) =
      *(int4*)(smem + (nr<<7) + (gc<<3));
  }
}

extern "C" void kernel_launch(void* const* d_in, const int* in_sizes, int n_in,
                              void* d_out, int out_size, void* d_ws, size_t ws_size,
                              hipStream_t stream){
  const float* x      = (const float*)d_in[0];
  const float* norm_w = (const float*)d_in[1];
  const float* norm_b = (const float*)d_in[2];
  const float* qkv_w  = (const float*)d_in[3];
  const float* qkv_b  = (const float*)d_in[4];
  const float* proj_w = (const float*)d_in[5];
  const float* proj_b = (const float*)d_in[6];
  float* out = (float*)d_out;

  u16* h_t   = (u16*)d_ws;                                  // [16][1024][512]
  u16* qk_t  = h_t  + (size_t)16*1024*512;                  // [16][1024][1024]
  u16* v_ws  = qk_t + (size_t)16*1024*1024;                 // [16][512][1024]
  u16* wq_bf = v_ws + (size_t)16*512*1024;                  // [1536][512]
  u16* wp_bf = wq_bf + (size_t)1536*512;                    // [512][512]
  u16* attnout = h_t;                                       // reuse

  pre_kernel<<<1536, 256, 0, stream>>>(x, norm_w, norm_b, h_t,
                                       qkv_w, wq_bf, 1536*512, proj_w, wp_bf, 512*512);

  gemm_qkv_kernel<<<dim3(6,8,16), 256, 0, stream>>>(h_t, wq_bf, qkv_b, qk_t, v_ws);

  attn_kernel<<<512, 256, 0, stream>>>(qk_t, v_ws, attnout);

  gemm_bt_kernel<<<dim3(8,4,16), 256, 0, stream>>>(
      wp_bf, 0, attnout, (long long)1024*512,
      nullptr, out, (long long)512*1024, proj_b, nullptr, x, (long long)512*1024, 512, 1024, 512);
}

// Round 11
// 199.252 us; speedup vs baseline: 1.0547x; 1.0266x over previous
//
#include <hip/hip_runtime.h>

typedef __bf16 v8bf __attribute__((ext_vector_type(8)));
typedef float  v4f  __attribute__((ext_vector_type(4)));
typedef float  v16f __attribute__((ext_vector_type(16)));
typedef unsigned short u16;

__device__ __forceinline__ u16 f2bf(float f){
  __bf16 h = (__bf16)f;
  union { __bf16 h; u16 u; } c; c.h = h; return c.u;
}
__device__ __forceinline__ v4f v4zero(){ v4f z; z[0]=0.f; z[1]=0.f; z[2]=0.f; z[3]=0.f; return z; }

#define MFMA16(a,b,c) __builtin_amdgcn_mfma_f32_16x16x32_bf16((a),(b),(c),0,0,0)
#define MFMA32(a,b,c) __builtin_amdgcn_mfma_f32_32x32x16_bf16((a),(b),(c),0,0,0)

// async global->LDS, 16B per lane; LDS dest = wave-uniform base + lane*16
__device__ __forceinline__ void gl_lds16(const u16* g, u16* l){
  __builtin_amdgcn_global_load_lds((const __attribute__((address_space(1))) void*)g,
                                   (__attribute__((address_space(3))) void*)l, 16, 0, 0);
}

// v_cvt_pk_bf16_f32: pack two f32 -> one u32 of 2 bf16 (no builtin on gfx950)
__device__ __forceinline__ unsigned int pkbf(float lo, float hi){
  unsigned int r;
  asm("v_cvt_pk_bf16_f32 %0, %1, %2" : "=v"(r) : "v"(lo), "v"(hi));
  return r;
}

// ============ Merged: GroupNorm (blocks 0..511) + f32->bf16 weight convert (blocks 512..1535) ============
__global__ __launch_bounds__(256) void pre_kernel(
    const float* __restrict__ x, const float* __restrict__ nw, const float* __restrict__ nbv,
    u16* __restrict__ h_t,
    const float* __restrict__ wa, u16* __restrict__ da, int na,
    const float* __restrict__ wb, u16* __restrict__ db, int nbn)
{
  __shared__ float xs[16*1028 + 16];
  const int bid = blockIdx.x;
  const int tid = threadIdx.x;

  if (bid >= 512){                      // ---- weight convert branch ----
    int i = ((bid - 512)*256 + tid)*4;
    const float* s; u16* d; int off;
    if (i < na){ s = wa; d = da; off = i; }
    else { off = i - na; if (off >= nbn) return; s = wb; d = db; }
    float4 v = *(const float4*)(s + off);
    ushort4 o;
    o.x = f2bf(v.x); o.y = f2bf(v.y); o.z = f2bf(v.z); o.w = f2bf(v.w);
    *(ushort4*)(d + off) = o;
    return;
  }

  // ---- GroupNorm: stats + apply + transpose ----
  const int b = bid >> 5, g = bid & 31, c0 = g*16;
  const float* base = x + (size_t)(b*512 + c0)*1024;

  float s = 0.f, ss = 0.f;
  #pragma unroll
  for (int it = 0; it < 16; ++it){
    float4 v = *(const float4*)(base + it*1024 + tid*4);
    s  += v.x + v.y + v.z + v.w;
    ss += v.x*v.x + v.y*v.y + v.z*v.z + v.w*v.w;
    *(float4*)(xs + it*1028 + tid*4) = v;
  }
  #pragma unroll
  for (int off = 32; off > 0; off >>= 1){ s += __shfl_down(s, off); ss += __shfl_down(ss, off); }
  float* red = xs + 16*1028;
  int w = tid >> 6;
  if ((tid & 63) == 0){ red[w] = s; red[4+w] = ss; }
  __syncthreads();
  if (tid == 0){
    float S  = red[0]+red[1]+red[2]+red[3];
    float SS = red[4]+red[5]+red[6]+red[7];
    float mean = S * (1.f/16384.f);
    float var  = SS * (1.f/16384.f) - mean*mean;
    red[8] = mean;
    red[9] = rsqrtf(var + 1e-5f);
  }
  __syncthreads();
  const float mean = red[8], rstd = red[9];

  const int half = tid & 1, nbase = tid >> 1;
  float wv[8], bv[8];
  #pragma unroll
  for (int cl = 0; cl < 8; ++cl){
    int c = c0 + half*8 + cl;
    wv[cl] = nw[c] * rstd;
    bv[cl] = nbv[c] - mean * wv[cl];
  }
  #pragma unroll
  for (int p = 0; p < 8; ++p){
    int n = nbase + p*128;
    alignas(16) u16 tmp[8];
    #pragma unroll
    for (int cl = 0; cl < 8; ++cl)
      tmp[cl] = f2bf(xs[(half*8 + cl)*1028 + n] * wv[cl] + bv[cl]);
    *(int4*)(h_t + ((size_t)b*1024 + n)*512 + c0 + half*8) = *(int4*)tmp;
  }
}

// ============ Fused QKV GEMM, double-buffered BK=32, 1 barrier/iter, 3 blocks/CU ============
__global__ __launch_bounds__(256,3) void gemm_qkv_kernel(
    const u16* __restrict__ A,       // h_t  [16][1024][512]
    const u16* __restrict__ B,       // wq_bf [1536][512]
    const float* __restrict__ bias,  // qkv_b [1536] f32
    u16* __restrict__ qk_t, u16* __restrict__ v_ws)
{
  __shared__ u16 smem[24576];    // 49,152 B: 2 x (A 4096 + B 8192 u16)
  const int tid = threadIdx.x, w = tid>>6, lane = tid&63, col = lane&15, quad = lane>>4;
  const int m0 = blockIdx.y*128;       // n
  const int n0 = blockIdx.x*256;       // o
  const int b  = blockIdx.z;
  const int lr = lane>>2;
  const int gsw = ((lane&3) ^ (lr&3))*8;
  const u16* Ag = A + ((size_t)b*1024 + m0 + w*32 + lr)*512 + gsw;
  const u16* Bg = B + (size_t)(n0 + w*64 + lr)*512 + gsw;
  const int mw = (w&1)*64, nw = (w>>1)*128;
  const int fsw = (quad ^ (col&3))*8;

  v4f acc[4][8];
  #pragma unroll
  for (int i=0;i<4;++i)
    #pragma unroll
    for (int j=0;j<8;++j) acc[i][j] = v4zero();

  {
    u16* Ab = smem + (w*32)*32;
    u16* Bb = smem + 4096 + (w*64)*32;
    #pragma unroll
    for (int p = 0; p < 2; ++p) gl_lds16(Ag + (size_t)(p*16)*512, Ab + p*512);
    #pragma unroll
    for (int p = 0; p < 4; ++p) gl_lds16(Bg + (size_t)(p*16)*512, Bb + p*512);
  }

  for (int kt = 0; kt < 16; ++kt){
    __syncthreads();
    if (kt < 15){
      u16* Ab = smem + ((kt+1)&1)*12288 + (w*32)*32;
      u16* Bb = smem + ((kt+1)&1)*12288 + 4096 + (w*64)*32;
      int ko = (kt+1)*32;
      #pragma unroll
      for (int p = 0; p < 2; ++p) gl_lds16(Ag + (size_t)(p*16)*512 + ko, Ab + p*512);
      #pragma unroll
      for (int p = 0; p < 4; ++p) gl_lds16(Bg + (size_t)(p*16)*512 + ko, Bb + p*512);
    }
    const u16* As = smem + (kt&1)*12288;
    const u16* Bs = As + 4096;
    v8bf a[4];
    #pragma unroll
    for (int i = 0; i < 4; ++i) a[i] = *(const v8bf*)(As + (mw+i*16+col)*32 + fsw);
    #pragma unroll
    for (int h2 = 0; h2 < 2; ++h2){
      v8bf bb[4];
      #pragma unroll
      for (int j = 0; j < 4; ++j) bb[j] = *(const v8bf*)(Bs + (nw+(h2*4+j)*16+col)*32 + fsw);
      #pragma unroll
      for (int i = 0; i < 4; ++i)
        #pragma unroll
        for (int j = 0; j < 4; ++j)
          acc[i][h2*4+j] = MFMA16(a[i], bb[j], acc[i][h2*4+j]);
    }
  }
  __syncthreads();

  float bc[8];
  #pragma unroll
  for (int j = 0; j < 8; ++j)
    bc[j] = bias[n0 + nw + j*16 + col];

  if (n0 < 1024){
    u16* Cs = smem + w*(64*72);
    #pragma unroll
    for (int half = 0; half < 2; ++half){
      #pragma unroll
      for (int i = 0; i < 4; ++i)
        #pragma unroll
        for (int jj = 0; jj < 4; ++jj)
          #pragma unroll
          for (int r = 0; r < 4; ++r)
            Cs[(i*16+quad*4+r)*72 + jj*16+col] = f2bf(acc[i][half*4+jj][r] + bc[half*4+jj]);
      u16* dst = qk_t + (size_t)b*1024*1024;
      #pragma unroll
      for (int p = 0; p < 8; ++p){
        int rl = p*8 + (lane>>3), cl = (lane&7)*8;
        *(int4*)(dst + (size_t)(m0+mw+rl)*1024 + n0+nw+half*64+cl) = *(int4*)(Cs + rl*72 + cl);
      }
    }
  } else {
    u16* Ct = smem + w*(64*80);
    #pragma unroll
    for (int half = 0; half < 2; ++half){
      #pragma unroll
      for (int i = 0; i < 4; ++i)
        #pragma unroll
        for (int jj = 0; jj < 4; ++jj)
          #pragma unroll
          for (int r = 0; r < 4; ++r)
            Ct[(jj*16+col)*80 + i*16+quad*4+r] = f2bf(acc[i][half*4+jj][r] + bc[half*4+jj]);
      u16* dst = v_ws + (size_t)b*512*1024;
      #pragma unroll
      for (int p = 0; p < 8; ++p){
        int rl = p*8 + (lane>>3), cl = (lane&7)*8;
        *(int4*)(dst + (size_t)(n0-1024 + nw + half*64 + rl)*1024 + m0+mw+cl) = *(int4*)(Ct + rl*80 + cl);
      }
    }
  }
}

// ============ Generic bf16 GEMM (proj): dbuf BK=64, 1 barrier/iter, float4 epilogue ============
__global__ __launch_bounds__(256,2) void gemm_bt_kernel(
    const u16* __restrict__ A, long long sA,
    const u16* __restrict__ B, long long sB,
    u16* __restrict__ Cbf, float* __restrict__ Cf, long long sC,
    const float* __restrict__ bias_row,
    const float* __restrict__ bias_col,
    const float* __restrict__ residf, long long sR,
    int M, int N, int K)
{
  __shared__ u16 smem[32768];   // 65,536 B: 2 x (A 8192 + B 8192 u16)
  const int tid = threadIdx.x, w = tid>>6, lane = tid&63, col = lane&15, quad = lane>>4;
  const int m0 = blockIdx.y*128, n0 = blockIdx.x*128;
  const int lr8 = lane>>3;
  const int gsw = ((lane&7) ^ lr8)*8;
  const u16* Ag = A + (size_t)blockIdx.z*sA + (size_t)(m0 + w*32 + lr8)*K + gsw;
  const u16* Bg = B + (size_t)blockIdx.z*sB + (size_t)(n0 + w*32 + lr8)*K + gsw;
  const int mw = (w&1)*64, nw = (w>>1)*64;
  const int csw = col&7;
  const int nt = K >> 6;

  v4f acc[4][4];
  #pragma unroll
  for (int i=0;i<4;++i)
    #pragma unroll
    for (int j=0;j<4;++j) acc[i][j] = v4zero();

  {
    u16* Ab = smem + (w*32)*64;
    u16* Bb = smem + 8192 + (w*32)*64;
    #pragma unroll
    for (int p = 0; p < 4; ++p){
      gl_lds16(Ag + (size_t)(p*8)*K, Ab + p*512);
      gl_lds16(Bg + (size_t)(p*8)*K, Bb + p*512);
    }
  }

  for (int kt = 0; kt < nt; ++kt){
    __syncthreads();
    if (kt+1 < nt){
      u16* Ab = smem + ((kt+1)&1)*16384 + (w*32)*64;
      u16* Bb = smem + ((kt+1)&1)*16384 + 8192 + (w*32)*64;
      int ko = (kt+1)*64;
      #pragma unroll
      for (int p = 0; p < 4; ++p){
        gl_lds16(Ag + (size_t)(p*8)*K + ko, Ab + p*512);
        gl_lds16(Bg + (size_t)(p*8)*K + ko, Bb + p*512);
      }
    }
    const u16* As = smem + (kt&1)*16384;
    const u16* Bs = As + 8192;
    #pragma unroll
    for (int kh = 0; kh < 2; ++kh){
      const int fs = ((kh*4 + quad) ^ csw)*8;
      v8bf a[4], bb[4];
      #pragma unroll
      for (int i = 0; i < 4; ++i) a[i]  = *(const v8bf*)(As + (mw+i*16+col)*64 + fs);
      #pragma unroll
      for (int j = 0; j < 4; ++j) bb[j] = *(const v8bf*)(Bs + (nw+j*16+col)*64 + fs);
      #pragma unroll
      for (int i = 0; i < 4; ++i)
        #pragma unroll
        for (int j = 0; j < 4; ++j)
          acc[i][j] = MFMA16(a[i], bb[j], acc[i][j]);
    }
  }
  __syncthreads();

  float br[4][4], bc[4];
  #pragma unroll
  for (int i = 0; i < 4; ++i)
    #pragma unroll
    for (int r = 0; r < 4; ++r)
      br[i][r] = bias_row ? bias_row[m0+mw+i*16+quad*4+r] : 0.f;
  #pragma unroll
  for (int j = 0; j < 4; ++j)
    bc[j] = bias_col ? bias_col[n0+nw+j*16+col] : 0.f;

  if (Cf){
    // float4 epilogue: per-wave LDS bounce in two 32-row halves -> 16B coalesced
    // residual loads + stores (was 64+64 scalar dword ops per thread; now 16+16 x16B).
    float* Cb = Cf + (size_t)blockIdx.z*sC;
    const float* Rb = residf ? residf + (size_t)blockIdx.z*sR : nullptr;
    float* fsh = (float*)smem + w*2176;   // [32][68] f32 per wave (34,816 B total)
    #pragma unroll
    for (int hh = 0; hh < 2; ++hh){
      #pragma unroll
      for (int ii = 0; ii < 2; ++ii){
        int i = hh*2 + ii;
        #pragma unroll
        for (int r = 0; r < 4; ++r){
          int lrow = ii*16 + quad*4 + r;
          #pragma unroll
          for (int j = 0; j < 4; ++j)
            fsh[lrow*68 + j*16 + col] = acc[i][j][r] + br[i][r] + bc[j];
        }
      }
      __syncthreads();
      #pragma unroll
      for (int p = 0; p < 8; ++p){
        int rl = p*4 + (lane>>4);          // 0..31
        int cl = (lane&15)*4;              // 0..60
        size_t goff = (size_t)(m0+mw+hh*32+rl)*N + n0+nw+cl;
        float4 v = *(const float4*)(fsh + rl*68 + cl);
        if (Rb){
          float4 rv = *(const float4*)(Rb + goff);
          v.x += rv.x; v.y += rv.y; v.z += rv.z; v.w += rv.w;
        }
        *(float4*)(Cb + goff) = v;
      }
      __syncthreads();
    }
  } else {
    u16* Cs = smem + w*(64*72);
    #pragma unroll
    for (int i = 0; i < 4; ++i)
      #pragma unroll
      for (int j = 0; j < 4; ++j)
        #pragma unroll
        for (int r = 0; r < 4; ++r)
          Cs[(i*16+quad*4+r)*72 + j*16+col] = f2bf(acc[i][j][r] + br[i][r] + bc[j]);
    __syncthreads();
    u16* Cb = Cbf + (size_t)blockIdx.z*sC;
    #pragma unroll
    for (int p = 0; p < 8; ++p){
      int rl = p*8 + (lane>>3), cl = (lane&7)*8;
      size_t goff = (size_t)(m0+mw+rl)*N + n0+nw+cl;
      *(int4*)(Cb + goff) = *(int4*)(Cs + rl*72 + cl);
    }
  }
}

// ============ Fused flash attention: R4 structure + 4-chain QK accumulators (best: ~47us) ============
// qk[b][n][0..511]=q, [512..1023]=k; vv[b][c_all][m]; out[b][n][c_all]
// flat grid 512 x 256: qt=id>>6, bh=id&63. 2 blocks/CU (grid-limited).
// B1 -> V-pf(t+1) -> QK(t) -> B2 -> K-pf(t+1) -> exp/pack -> PV(t).
// In-register softmax via swapped QK^T (T12: cvt_pk + permlane32_swap), no P buffer.
__global__ __launch_bounds__(256,2) void attn_kernel(const u16* __restrict__ qk, const u16* __restrict__ vv,
                                                     u16* __restrict__ outp){
  __shared__ u16 smem[24576];        // 48KB: Ks [64][128] (16KB) + Vs 2x[128][64] (32KB)
  u16* Ks = smem;                    // single buffer
  u16* Vs = smem + 8192;             // double buffer
  const int id = blockIdx.x;
  const int qt = id >> 6, bh = id & 63, b = bh >> 2, h = bh & 3;
  const int n0 = qt*128;
  const int tid = threadIdx.x, w = tid>>6, lane = tid&63;
  const int nl = lane & 31, hi = lane >> 5;
  const int key = nl & 7;
  const size_t bq = (size_t)b*1024*1024;
  const float scale2 = 0.12751742f;  // (1/sqrt(128)) * log2(e)

  // Q as B-operand fragments in registers: col n = n0+w*32+nl, k granule kk*2+hi
  v8bf qf[8];
  {
    const u16* qbase = qk + bq + (size_t)(n0 + w*32 + nl)*1024 + h*128 + hi*8;
    #pragma unroll
    for (int kk = 0; kk < 8; ++kk)
      qf[kk] = *(const v8bf*)(qbase + kk*16);
  }

  v16f o[4];
  #pragma unroll
  for (int j=0;j<4;++j)
    #pragma unroll
    for (int r=0;r<16;++r) o[j][r] = 0.f;
  float ls0 = 0.f, ls1 = 0.f;

  // staging lane constants (swizzle folded into global source granule)
  const int krow = w*4 + (lane>>4);
  const int kgr  = (lane&15) ^ (krow&7);
  const u16* kg_base = qk + bq + (size_t)krow*1024 + 512 + h*128 + kgr*8;
  const int vrow = w*8 + (lane>>3);
  const int vgr  = (lane&7) ^ (vrow&7);
  const u16* vg_base = vv + ((size_t)b*512 + h*128 + vrow)*1024 + vgr*8;

  // prologue: stage K(0) and V(0)
  #pragma unroll
  for (int p = 0; p < 4; ++p)
    gl_lds16(kg_base + (size_t)(p*16)*1024, Ks + (w*4)*128 + p*2048);
  #pragma unroll
  for (int p = 0; p < 4; ++p)
    gl_lds16(vg_base + (size_t)(p*32)*1024, Vs + (w*8)*64 + p*2048);

  for (int t = 0; t < 16; ++t){
    const int mt = t*64;
    __syncthreads();                       // B1: K(t) and V(t) resident

    if (t < 15){                           // V prefetch t+1 -> other buffer; drains at B2 (covered by QK)
      int mt2 = mt + 64;
      u16* vl = Vs + (((t+1)&1)<<13) + (w*8)*64;
      #pragma unroll
      for (int p = 0; p < 4; ++p)
        gl_lds16(vg_base + (size_t)(p*32)*1024 + mt2, vl + p*2048);
    }

    // S^T = K Q^T (raw), 4 independent accumulation chains (k-parity split)
    v16f s0a, s0b, s1a, s1b;
    #pragma unroll
    for (int r=0;r<16;++r){ s0a[r]=0.f; s0b[r]=0.f; s1a[r]=0.f; s1b[r]=0.f; }
    __builtin_amdgcn_s_setprio(1);
    #pragma unroll
    for (int kk = 0; kk < 8; ++kk){
      int g = (((kk*2 + hi) ^ key) << 3);
      v8bf k0 = *(const v8bf*)(Ks + (nl<<7) + g);
      v8bf k1 = *(const v8bf*)(Ks + ((32+nl)<<7) + g);
      if (kk & 1){
        s0b = MFMA32(k0, qf[kk], s0b);
        s1b = MFMA32(k1, qf[kk], s1b);
      } else {
        s0a = MFMA32(k0, qf[kk], s0a);
        s1a = MFMA32(k1, qf[kk], s1a);
      }
    }
    __builtin_amdgcn_s_setprio(0);

    __syncthreads();                       // B2: all waves consumed K(t); Ks free

    if (t < 15){                           // K prefetch t+1 -> Ks; drains at B1' (covered by exp+PV)
      int mt2 = mt + 64;
      #pragma unroll
      for (int p = 0; p < 4; ++p)
        gl_lds16(kg_base + (size_t)(mt2 + p*16)*1024, Ks + (w*4)*128 + p*2048);
    }

    // merge chains, p = exp2(s*scale2), 2 independent lane-local sum chains
    v16f s0, s1;
    #pragma unroll
    for (int r = 0; r < 16; ++r){
      s0[r] = __builtin_amdgcn_exp2f((s0a[r] + s0b[r])*scale2);
      s1[r] = __builtin_amdgcn_exp2f((s1a[r] + s1b[r])*scale2);
      ls0 += s0[r];
      ls1 += s1[r];
    }

    // O += P V^T, P packed to A-frags in-register (cvt_pk + permlane32_swap)
    const u16* Vc = Vs + ((t&1)<<13);
    #pragma unroll
    for (int half = 0; half < 2; ++half){
      const v16f& ps = half ? s1 : s0;
      #pragma unroll
      for (int sel = 0; sel < 2; ++sel){
        const int sb = sel*8;
        unsigned int pA = pkbf(ps[sb+0], ps[sb+1]);
        unsigned int pB = pkbf(ps[sb+2], ps[sb+3]);
        unsigned int pC = pkbf(ps[sb+4], ps[sb+5]);
        unsigned int pD = pkbf(ps[sb+6], ps[sb+7]);
        asm("v_permlane32_swap_b32 %0, %1" : "+v"(pA), "+v"(pC));
        asm("v_permlane32_swap_b32 %0, %1" : "+v"(pB), "+v"(pD));
        union { v8bf v; unsigned int u[4]; } pa;
        pa.u[0] = pA; pa.u[1] = pB; pa.u[2] = pC; pa.u[3] = pD;
        const int kkv = half*2 + sel;
        const int gv = (((kkv*2 + hi) ^ key) << 3);
        __builtin_amdgcn_s_setprio(1);
        #pragma unroll
        for (int j = 0; j < 4; ++j){
          v8bf bv = *(const v8bf*)(Vc + ((j*32 + nl)<<6) + gv);
          o[j] = MFMA32(pa.v, bv, o[j]);
        }
        __builtin_amdgcn_s_setprio(0);
      }
    }
  }
  __syncthreads();

  // full row-sum for q-row nl (other half of m lives in lane^32), then redistribute
  // 1/l to the 32x32 C/D row layout: row(reg) = (reg&3) + 8*(reg>>2) + 4*hi
  float lsum = ls0 + ls1;
  lsum += __shfl_xor(lsum, 32);
  float invl[16];
  #pragma unroll
  for (int r = 0; r < 16; ++r){
    int nr = (r&3) + 8*(r>>2) + 4*hi;
    invl[r] = 1.f / __shfl(lsum, nr);
  }

  // bounce O through LDS (swizzled [128][128]) for coalesced 16B stores
  #pragma unroll
  for (int j = 0; j < 4; ++j)
    #pragma unroll
    for (int r = 0; r < 16; ++r){
      int rr = w*32 + (r&3) + 8*(r>>2) + 4*hi;
      int c  = j*32 + nl;
      smem[(rr<<7) + ((((c>>3) ^ (rr&7))<<3)) + (c&7)] = f2bf(o[j][r] * invl[r]);
    }
  __syncthreads();
  #pragma unroll
  for (int p = 0; p < 8; ++p){
    int nr = p*16 + (tid>>4);
    int gc = (tid&15) ^ (nr&7);
    *(int4*)(outp + ((size_t)b*1024 + n0 + nr)*512 + h*128 + ((tid&15)<<3)) =
      *(int4*)(smem + (nr<<7) + (gc<<3));
  }
}

extern "C" void kernel_launch(void* const* d_in, const int* in_sizes, int n_in,
                              void* d_out, int out_size, void* d_ws, size_t ws_size,
                              hipStream_t stream){
  const float* x      = (const float*)d_in[0];
  const float* norm_w = (const float*)d_in[1];
  const float* norm_b = (const float*)d_in[2];
  const float* qkv_w  = (const float*)d_in[3];
  const float* qkv_b  = (const float*)d_in[4];
  const float* proj_w = (const float*)d_in[5];
  const float* proj_b = (const float*)d_in[6];
  float* out = (float*)d_out;

  u16* h_t   = (u16*)d_ws;                                  // [16][1024][512]
  u16* qk_t  = h_t  + (size_t)16*1024*512;                  // [16][1024][1024]
  u16* v_ws  = qk_t + (size_t)16*1024*1024;                 // [16][512][1024]
  u16* wq_bf = v_ws + (size_t)16*512*1024;                  // [1536][512]
  u16* wp_bf = wq_bf + (size_t)1536*512;                    // [512][512]
  u16* attnout = h_t;                                       // reuse

  pre_kernel<<<1536, 256, 0, stream>>>(x, norm_w, norm_b, h_t,
                                       qkv_w, wq_bf, 1536*512, proj_w, wp_bf, 512*512);

  gemm_qkv_kernel<<<dim3(6,8,16), 256, 0, stream>>>(h_t, wq_bf, qkv_b, qk_t, v_ws);

  attn_kernel<<<512, 256, 0, stream>>>(qk_t, v_ws, attnout);

  gemm_bt_kernel<<<dim3(8,4,16), 256, 0, stream>>>(
      wp_bf, 0, attnout, (long long)1024*512,
      nullptr, out, (long long)512*1024, proj_b, nullptr, x, (long long)512*1024, 512, 1024, 512);
}

// Round 12
// 194.170 us; speedup vs baseline: 1.0823x; 1.0262x over previous
//
#include <hip/hip_runtime.h>

typedef __bf16 v8bf __attribute__((ext_vector_type(8)));
typedef float  v4f  __attribute__((ext_vector_type(4)));
typedef float  v16f __attribute__((ext_vector_type(16)));
typedef unsigned short u16;

__device__ __forceinline__ u16 f2bf(float f){
  __bf16 h = (__bf16)f;
  union { __bf16 h; u16 u; } c; c.h = h; return c.u;
}
__device__ __forceinline__ v4f v4zero(){ v4f z; z[0]=0.f; z[1]=0.f; z[2]=0.f; z[3]=0.f; return z; }

#define MFMA16(a,b,c) __builtin_amdgcn_mfma_f32_16x16x32_bf16((a),(b),(c),0,0,0)
#define MFMA32(a,b,c) __builtin_amdgcn_mfma_f32_32x32x16_bf16((a),(b),(c),0,0,0)

// async global->LDS, 16B per lane; LDS dest = wave-uniform base + lane*16
__device__ __forceinline__ void gl_lds16(const u16* g, u16* l){
  __builtin_amdgcn_global_load_lds((const __attribute__((address_space(1))) void*)g,
                                   (__attribute__((address_space(3))) void*)l, 16, 0, 0);
}

// v_cvt_pk_bf16_f32: pack two f32 -> one u32 of 2 bf16 (no builtin on gfx950)
__device__ __forceinline__ unsigned int pkbf(float lo, float hi){
  unsigned int r;
  asm("v_cvt_pk_bf16_f32 %0, %1, %2" : "=v"(r) : "v"(lo), "v"(hi));
  return r;
}

// ============ Merged: GroupNorm (blocks 0..511) + f32->bf16 weight convert (blocks 512..1535) ============
__global__ __launch_bounds__(256) void pre_kernel(
    const float* __restrict__ x, const float* __restrict__ nw, const float* __restrict__ nbv,
    u16* __restrict__ h_t,
    const float* __restrict__ wa, u16* __restrict__ da, int na,
    const float* __restrict__ wb, u16* __restrict__ db, int nbn)
{
  __shared__ float xs[16*1028 + 16];
  const int bid = blockIdx.x;
  const int tid = threadIdx.x;

  if (bid >= 512){                      // ---- weight convert branch ----
    int i = ((bid - 512)*256 + tid)*4;
    const float* s; u16* d; int off;
    if (i < na){ s = wa; d = da; off = i; }
    else { off = i - na; if (off >= nbn) return; s = wb; d = db; }
    float4 v = *(const float4*)(s + off);
    ushort4 o;
    o.x = f2bf(v.x); o.y = f2bf(v.y); o.z = f2bf(v.z); o.w = f2bf(v.w);
    *(ushort4*)(d + off) = o;
    return;
  }

  // ---- GroupNorm: stats + apply + transpose ----
  const int b = bid >> 5, g = bid & 31, c0 = g*16;
  const float* base = x + (size_t)(b*512 + c0)*1024;

  float s = 0.f, ss = 0.f;
  #pragma unroll
  for (int it = 0; it < 16; ++it){
    float4 v = *(const float4*)(base + it*1024 + tid*4);
    s  += v.x + v.y + v.z + v.w;
    ss += v.x*v.x + v.y*v.y + v.z*v.z + v.w*v.w;
    *(float4*)(xs + it*1028 + tid*4) = v;
  }
  #pragma unroll
  for (int off = 32; off > 0; off >>= 1){ s += __shfl_down(s, off); ss += __shfl_down(ss, off); }
  float* red = xs + 16*1028;
  int w = tid >> 6;
  if ((tid & 63) == 0){ red[w] = s; red[4+w] = ss; }
  __syncthreads();
  if (tid == 0){
    float S  = red[0]+red[1]+red[2]+red[3];
    float SS = red[4]+red[5]+red[6]+red[7];
    float mean = S * (1.f/16384.f);
    float var  = SS * (1.f/16384.f) - mean*mean;
    red[8] = mean;
    red[9] = rsqrtf(var + 1e-5f);
  }
  __syncthreads();
  const float mean = red[8], rstd = red[9];

  const int half = tid & 1, nbase = tid >> 1;
  float wv[8], bv[8];
  #pragma unroll
  for (int cl = 0; cl < 8; ++cl){
    int c = c0 + half*8 + cl;
    wv[cl] = nw[c] * rstd;
    bv[cl] = nbv[c] - mean * wv[cl];
  }
  #pragma unroll
  for (int p = 0; p < 8; ++p){
    int n = nbase + p*128;
    alignas(16) u16 tmp[8];
    #pragma unroll
    for (int cl = 0; cl < 8; ++cl)
      tmp[cl] = f2bf(xs[(half*8 + cl)*1028 + n] * wv[cl] + bv[cl]);
    *(int4*)(h_t + ((size_t)b*1024 + n)*512 + c0 + half*8) = *(int4*)tmp;
  }
}

// ============ Fused QKV GEMM, double-buffered BK=32, 1 barrier/iter, 3 blocks/CU, XCD swizzle ============
// XCD-aware tile remap (T1): the 6 tiles sharing an A-panel (same m0,b) are consecutive in
// hardware linear id -> default round-robin scatters them over 6 XCDs, re-fetching each
// 128KB A-panel 6x past its private L2. Bijective swizzle (768%8==0) gives each XCD a
// contiguous 96-tile chunk (= 2 batches, all m0/n0): per-XCD A set 2MB <= 4MB L2.
__global__ __launch_bounds__(256,3) void gemm_qkv_kernel(
    const u16* __restrict__ A,       // h_t  [16][1024][512]
    const u16* __restrict__ B,       // wq_bf [1536][512]
    const float* __restrict__ bias,  // qkv_b [1536] f32
    u16* __restrict__ qk_t, u16* __restrict__ v_ws)
{
  __shared__ u16 smem[24576];    // 49,152 B: 2 x (A 4096 + B 8192 u16)
  const int tid = threadIdx.x, w = tid>>6, lane = tid&63, col = lane&15, quad = lane>>4;
  const int lin = blockIdx.x + 6*(blockIdx.y + 8*blockIdx.z);   // hardware linear id
  const int swz = (lin & 7)*96 + (lin >> 3);                    // same-XCD contiguous tiles
  const int n0 = (swz % 6)*256;        // o
  const int m0 = ((swz/6) & 7)*128;    // n
  const int b  = swz/48;
  const int lr = lane>>2;
  const int gsw = ((lane&3) ^ (lr&3))*8;
  const u16* Ag = A + ((size_t)b*1024 + m0 + w*32 + lr)*512 + gsw;
  const u16* Bg = B + (size_t)(n0 + w*64 + lr)*512 + gsw;
  const int mw = (w&1)*64, nw = (w>>1)*128;
  const int fsw = (quad ^ (col&3))*8;

  v4f acc[4][8];
  #pragma unroll
  for (int i=0;i<4;++i)
    #pragma unroll
    for (int j=0;j<8;++j) acc[i][j] = v4zero();

  {
    u16* Ab = smem + (w*32)*32;
    u16* Bb = smem + 4096 + (w*64)*32;
    #pragma unroll
    for (int p = 0; p < 2; ++p) gl_lds16(Ag + (size_t)(p*16)*512, Ab + p*512);
    #pragma unroll
    for (int p = 0; p < 4; ++p) gl_lds16(Bg + (size_t)(p*16)*512, Bb + p*512);
  }

  for (int kt = 0; kt < 16; ++kt){
    __syncthreads();
    if (kt < 15){
      u16* Ab = smem + ((kt+1)&1)*12288 + (w*32)*32;
      u16* Bb = smem + ((kt+1)&1)*12288 + 4096 + (w*64)*32;
      int ko = (kt+1)*32;
      #pragma unroll
      for (int p = 0; p < 2; ++p) gl_lds16(Ag + (size_t)(p*16)*512 + ko, Ab + p*512);
      #pragma unroll
      for (int p = 0; p < 4; ++p) gl_lds16(Bg + (size_t)(p*16)*512 + ko, Bb + p*512);
    }
    const u16* As = smem + (kt&1)*12288;
    const u16* Bs = As + 4096;
    v8bf a[4];
    #pragma unroll
    for (int i = 0; i < 4; ++i) a[i] = *(const v8bf*)(As + (mw+i*16+col)*32 + fsw);
    #pragma unroll
    for (int h2 = 0; h2 < 2; ++h2){
      v8bf bb[4];
      #pragma unroll
      for (int j = 0; j < 4; ++j) bb[j] = *(const v8bf*)(Bs + (nw+(h2*4+j)*16+col)*32 + fsw);
      #pragma unroll
      for (int i = 0; i < 4; ++i)
        #pragma unroll
        for (int j = 0; j < 4; ++j)
          acc[i][h2*4+j] = MFMA16(a[i], bb[j], acc[i][h2*4+j]);
    }
  }
  __syncthreads();

  float bc[8];
  #pragma unroll
  for (int j = 0; j < 8; ++j)
    bc[j] = bias[n0 + nw + j*16 + col];

  if (n0 < 1024){
    u16* Cs = smem + w*(64*72);
    #pragma unroll
    for (int half = 0; half < 2; ++half){
      #pragma unroll
      for (int i = 0; i < 4; ++i)
        #pragma unroll
        for (int jj = 0; jj < 4; ++jj)
          #pragma unroll
          for (int r = 0; r < 4; ++r)
            Cs[(i*16+quad*4+r)*72 + jj*16+col] = f2bf(acc[i][half*4+jj][r] + bc[half*4+jj]);
      u16* dst = qk_t + (size_t)b*1024*1024;
      #pragma unroll
      for (int p = 0; p < 8; ++p){
        int rl = p*8 + (lane>>3), cl = (lane&7)*8;
        *(int4*)(dst + (size_t)(m0+mw+rl)*1024 + n0+nw+half*64+cl) = *(int4*)(Cs + rl*72 + cl);
      }
    }
  } else {
    u16* Ct = smem + w*(64*80);
    #pragma unroll
    for (int half = 0; half < 2; ++half){
      #pragma unroll
      for (int i = 0; i < 4; ++i)
        #pragma unroll
        for (int jj = 0; jj < 4; ++jj)
          #pragma unroll
          for (int r = 0; r < 4; ++r)
            Ct[(jj*16+col)*80 + i*16+quad*4+r] = f2bf(acc[i][half*4+jj][r] + bc[half*4+jj]);
      u16* dst = v_ws + (size_t)b*512*1024;
      #pragma unroll
      for (int p = 0; p < 8; ++p){
        int rl = p*8 + (lane>>3), cl = (lane&7)*8;
        *(int4*)(dst + (size_t)(n0-1024 + nw + half*64 + rl)*1024 + m0+mw+cl) = *(int4*)(Ct + rl*80 + cl);
      }
    }
  }
}

// ============ Generic bf16 GEMM (proj): dbuf BK=64, float4 epilogue, XCD swizzle ============
__global__ __launch_bounds__(256,2) void gemm_bt_kernel(
    const u16* __restrict__ A, long long sA,
    const u16* __restrict__ B, long long sB,
    u16* __restrict__ Cbf, float* __restrict__ Cf, long long sC,
    const float* __restrict__ bias_row,
    const float* __restrict__ bias_col,
    const float* __restrict__ residf, long long sR,
    int M, int N, int K)
{
  __shared__ u16 smem[32768];   // 65,536 B: 2 x (A 8192 + B 8192 u16)
  const int tid = threadIdx.x, w = tid>>6, lane = tid&63, col = lane&15, quad = lane>>4;
  // XCD-aware tile remap (T1), bijective when total%8==0 (else identity)
  const int gx = gridDim.x, gy = gridDim.y;
  const int total = gx*gy*gridDim.z;
  int lin = blockIdx.x + gx*(blockIdx.y + gy*blockIdx.z);
  int swz = (total % 8 == 0) ? (lin & 7)*(total >> 3) + (lin >> 3) : lin;
  const int bx = swz % gx, by = (swz/gx) % gy, bz = swz/(gx*gy);
  const int m0 = by*128, n0 = bx*128;
  const int lr8 = lane>>3;
  const int gsw = ((lane&7) ^ lr8)*8;
  const u16* Ag = A + (size_t)bz*sA + (size_t)(m0 + w*32 + lr8)*K + gsw;
  const u16* Bg = B + (size_t)bz*sB + (size_t)(n0 + w*32 + lr8)*K + gsw;
  const int mw = (w&1)*64, nw = (w>>1)*64;
  const int csw = col&7;
  const int nt = K >> 6;

  v4f acc[4][4];
  #pragma unroll
  for (int i=0;i<4;++i)
    #pragma unroll
    for (int j=0;j<4;++j) acc[i][j] = v4zero();

  {
    u16* Ab = smem + (w*32)*64;
    u16* Bb = smem + 8192 + (w*32)*64;
    #pragma unroll
    for (int p = 0; p < 4; ++p){
      gl_lds16(Ag + (size_t)(p*8)*K, Ab + p*512);
      gl_lds16(Bg + (size_t)(p*8)*K, Bb + p*512);
    }
  }

  for (int kt = 0; kt < nt; ++kt){
    __syncthreads();
    if (kt+1 < nt){
      u16* Ab = smem + ((kt+1)&1)*16384 + (w*32)*64;
      u16* Bb = smem + ((kt+1)&1)*16384 + 8192 + (w*32)*64;
      int ko = (kt+1)*64;
      #pragma unroll
      for (int p = 0; p < 4; ++p){
        gl_lds16(Ag + (size_t)(p*8)*K + ko, Ab + p*512);
        gl_lds16(Bg + (size_t)(p*8)*K + ko, Bb + p*512);
      }
    }
    const u16* As = smem + (kt&1)*16384;
    const u16* Bs = As + 8192;
    #pragma unroll
    for (int kh = 0; kh < 2; ++kh){
      const int fs = ((kh*4 + quad) ^ csw)*8;
      v8bf a[4], bb[4];
      #pragma unroll
      for (int i = 0; i < 4; ++i) a[i]  = *(const v8bf*)(As + (mw+i*16+col)*64 + fs);
      #pragma unroll
      for (int j = 0; j < 4; ++j) bb[j] = *(const v8bf*)(Bs + (nw+j*16+col)*64 + fs);
      #pragma unroll
      for (int i = 0; i < 4; ++i)
        #pragma unroll
        for (int j = 0; j < 4; ++j)
          acc[i][j] = MFMA16(a[i], bb[j], acc[i][j]);
    }
  }
  __syncthreads();

  float br[4][4], bc[4];
  #pragma unroll
  for (int i = 0; i < 4; ++i)
    #pragma unroll
    for (int r = 0; r < 4; ++r)
      br[i][r] = bias_row ? bias_row[m0+mw+i*16+quad*4+r] : 0.f;
  #pragma unroll
  for (int j = 0; j < 4; ++j)
    bc[j] = bias_col ? bias_col[n0+nw+j*16+col] : 0.f;

  if (Cf){
    // float4 epilogue: per-wave LDS bounce in two 32-row halves -> 16B coalesced
    float* Cb = Cf + (size_t)bz*sC;
    const float* Rb = residf ? residf + (size_t)bz*sR : nullptr;
    float* fsh = (float*)smem + w*2176;   // [32][68] f32 per wave (34,816 B total)
    #pragma unroll
    for (int hh = 0; hh < 2; ++hh){
      #pragma unroll
      for (int ii = 0; ii < 2; ++ii){
        int i = hh*2 + ii;
        #pragma unroll
        for (int r = 0; r < 4; ++r){
          int lrow = ii*16 + quad*4 + r;
          #pragma unroll
          for (int j = 0; j < 4; ++j)
            fsh[lrow*68 + j*16 + col] = acc[i][j][r] + br[i][r] + bc[j];
        }
      }
      __syncthreads();
      #pragma unroll
      for (int p = 0; p < 8; ++p){
        int rl = p*4 + (lane>>4);          // 0..31
        int cl = (lane&15)*4;              // 0..60
        size_t goff = (size_t)(m0+mw+hh*32+rl)*N + n0+nw+cl;
        float4 v = *(const float4*)(fsh + rl*68 + cl);
        if (Rb){
          float4 rv = *(const float4*)(Rb + goff);
          v.x += rv.x; v.y += rv.y; v.z += rv.z; v.w += rv.w;
        }
        *(float4*)(Cb + goff) = v;
      }
      __syncthreads();
    }
  } else {
    u16* Cs = smem + w*(64*72);
    #pragma unroll
    for (int i = 0; i < 4; ++i)
      #pragma unroll
      for (int j = 0; j < 4; ++j)
        #pragma unroll
        for (int r = 0; r < 4; ++r)
          Cs[(i*16+quad*4+r)*72 + j*16+col] = f2bf(acc[i][j][r] + br[i][r] + bc[j]);
    __syncthreads();
    u16* Cb = Cbf + (size_t)bz*sC;
    #pragma unroll
    for (int p = 0; p < 8; ++p){
      int rl = p*8 + (lane>>3), cl = (lane&7)*8;
      size_t goff = (size_t)(m0+mw+rl)*N + n0+nw+cl;
      *(int4*)(Cb + goff) = *(int4*)(Cs + rl*72 + cl);
    }
  }
}

// ============ Fused flash attention: R4 structure + 4-chain QK accumulators (best: ~47us) ============
// qk[b][n][0..511]=q, [512..1023]=k; vv[b][c_all][m]; out[b][n][c_all]
// flat grid 512 x 256: qt=id>>6, bh=id&63 -> same-(b,h) blocks land on the same XCD
// already (stride 64 == 0 mod 8). 2 blocks/CU (grid-limited).
// B1 -> V-pf(t+1) -> QK(t) -> B2 -> K-pf(t+1) -> exp/pack -> PV(t).
// In-register softmax via swapped QK^T (T12: cvt_pk + permlane32_swap), no P buffer.
__global__ __launch_bounds__(256,2) void attn_kernel(const u16* __restrict__ qk, const u16* __restrict__ vv,
                                                     u16* __restrict__ outp){
  __shared__ u16 smem[24576];        // 48KB: Ks [64][128] (16KB) + Vs 2x[128][64] (32KB)
  u16* Ks = smem;                    // single buffer
  u16* Vs = smem + 8192;             // double buffer
  const int id = blockIdx.x;
  const int qt = id >> 6, bh = id & 63, b = bh >> 2, h = bh & 3;
  const int n0 = qt*128;
  const int tid = threadIdx.x, w = tid>>6, lane = tid&63;
  const int nl = lane & 31, hi = lane >> 5;
  const int key = nl & 7;
  const size_t bq = (size_t)b*1024*1024;
  const float scale2 = 0.12751742f;  // (1/sqrt(128)) * log2(e)

  // Q as B-operand fragments in registers: col n = n0+w*32+nl, k granule kk*2+hi
  v8bf qf[8];
  {
    const u16* qbase = qk + bq + (size_t)(n0 + w*32 + nl)*1024 + h*128 + hi*8;
    #pragma unroll
    for (int kk = 0; kk < 8; ++kk)
      qf[kk] = *(const v8bf*)(qbase + kk*16);
  }

  v16f o[4];
  #pragma unroll
  for (int j=0;j<4;++j)
    #pragma unroll
    for (int r=0;r<16;++r) o[j][r] = 0.f;
  float ls0 = 0.f, ls1 = 0.f;

  // staging lane constants (swizzle folded into global source granule)
  const int krow = w*4 + (lane>>4);
  const int kgr  = (lane&15) ^ (krow&7);
  const u16* kg_base = qk + bq + (size_t)krow*1024 + 512 + h*128 + kgr*8;
  const int vrow = w*8 + (lane>>3);
  const int vgr  = (lane&7) ^ (vrow&7);
  const u16* vg_base = vv + ((size_t)b*512 + h*128 + vrow)*1024 + vgr*8;

  // prologue: stage K(0) and V(0)
  #pragma unroll
  for (int p = 0; p < 4; ++p)
    gl_lds16(kg_base + (size_t)(p*16)*1024, Ks + (w*4)*128 + p*2048);
  #pragma unroll
  for (int p = 0; p < 4; ++p)
    gl_lds16(vg_base + (size_t)(p*32)*1024, Vs + (w*8)*64 + p*2048);

  for (int t = 0; t < 16; ++t){
    const int mt = t*64;
    __syncthreads();                       // B1: K(t) and V(t) resident

    if (t < 15){                           // V prefetch t+1 -> other buffer; drains at B2 (covered by QK)
      int mt2 = mt + 64;
      u16* vl = Vs + (((t+1)&1)<<13) + (w*8)*64;
      #pragma unroll
      for (int p = 0; p < 4; ++p)
        gl_lds16(vg_base + (size_t)(p*32)*1024 + mt2, vl + p*2048);
    }

    // S^T = K Q^T (raw), 4 independent accumulation chains (k-parity split)
    v16f s0a, s0b, s1a, s1b;
    #pragma unroll
    for (int r=0;r<16;++r){ s0a[r]=0.f; s0b[r]=0.f; s1a[r]=0.f; s1b[r]=0.f; }
    __builtin_amdgcn_s_setprio(1);
    #pragma unroll
    for (int kk = 0; kk < 8; ++kk){
      int g = (((kk*2 + hi) ^ key) << 3);
      v8bf k0 = *(const v8bf*)(Ks + (nl<<7) + g);
      v8bf k1 = *(const v8bf*)(Ks + ((32+nl)<<7) + g);
      if (kk & 1){
        s0b = MFMA32(k0, qf[kk], s0b);
        s1b = MFMA32(k1, qf[kk], s1b);
      } else {
        s0a = MFMA32(k0, qf[kk], s0a);
        s1a = MFMA32(k1, qf[kk], s1a);
      }
    }
    __builtin_amdgcn_s_setprio(0);

    __syncthreads();                       // B2: all waves consumed K(t); Ks free

    if (t < 15){                           // K prefetch t+1 -> Ks; drains at B1' (covered by exp+PV)
      int mt2 = mt + 64;
      #pragma unroll
      for (int p = 0; p < 4; ++p)
        gl_lds16(kg_base + (size_t)(mt2 + p*16)*1024, Ks + (w*4)*128 + p*2048);
    }

    // merge chains, p = exp2(s*scale2), 2 independent lane-local sum chains
    v16f s0, s1;
    #pragma unroll
    for (int r = 0; r < 16; ++r){
      s0[r] = __builtin_amdgcn_exp2f((s0a[r] + s0b[r])*scale2);
      s1[r] = __builtin_amdgcn_exp2f((s1a[r] + s1b[r])*scale2);
      ls0 += s0[r];
      ls1 += s1[r];
    }

    // O += P V^T, P packed to A-frags in-register (cvt_pk + permlane32_swap)
    const u16* Vc = Vs + ((t&1)<<13);
    #pragma unroll
    for (int half = 0; half < 2; ++half){
      const v16f& ps = half ? s1 : s0;
      #pragma unroll
      for (int sel = 0; sel < 2; ++sel){
        const int sb = sel*8;
        unsigned int pA = pkbf(ps[sb+0], ps[sb+1]);
        unsigned int pB = pkbf(ps[sb+2], ps[sb+3]);
        unsigned int pC = pkbf(ps[sb+4], ps[sb+5]);
        unsigned int pD = pkbf(ps[sb+6], ps[sb+7]);
        asm("v_permlane32_swap_b32 %0, %1" : "+v"(pA), "+v"(pC));
        asm("v_permlane32_swap_b32 %0, %1" : "+v"(pB), "+v"(pD));
        union { v8bf v; unsigned int u[4]; } pa;
        pa.u[0] = pA; pa.u[1] = pB; pa.u[2] = pC; pa.u[3] = pD;
        const int kkv = half*2 + sel;
        const int gv = (((kkv*2 + hi) ^ key) << 3);
        __builtin_amdgcn_s_setprio(1);
        #pragma unroll
        for (int j = 0; j < 4; ++j){
          v8bf bv = *(const v8bf*)(Vc + ((j*32 + nl)<<6) + gv);
          o[j] = MFMA32(pa.v, bv, o[j]);
        }
        __builtin_amdgcn_s_setprio(0);
      }
    }
  }
  __syncthreads();

  // full row-sum for q-row nl (other half of m lives in lane^32), then redistribute
  // 1/l to the 32x32 C/D row layout: row(reg) = (reg&3) + 8*(reg>>2) + 4*hi
  float lsum = ls0 + ls1;
  lsum += __shfl_xor(lsum, 32);
  float invl[16];
  #pragma unroll
  for (int r = 0; r < 16; ++r){
    int nr = (r&3) + 8*(r>>2) + 4*hi;
    invl[r] = 1.f / __shfl(lsum, nr);
  }

  // bounce O through LDS (swizzled [128][128]) for coalesced 16B stores
  #pragma unroll
  for (int j = 0; j < 4; ++j)
    #pragma unroll
    for (int r = 0; r < 16; ++r){
      int rr = w*32 + (r&3) + 8*(r>>2) + 4*hi;
      int c  = j*32 + nl;
      smem[(rr<<7) + ((((c>>3) ^ (rr&7))<<3)) + (c&7)] = f2bf(o[j][r] * invl[r]);
    }
  __syncthreads();
  #pragma unroll
  for (int p = 0; p < 8; ++p){
    int nr = p*16 + (tid>>4);
    int gc = (tid&15) ^ (nr&7);
    *(int4*)(outp + ((size_t)b*1024 + n0 + nr)*512 + h*128 + ((tid&15)<<3)) =
      *(int4*)(smem + (nr<<7) + (gc<<3));
  }
}

extern "C" void kernel_launch(void* const* d_in, const int* in_sizes, int n_in,
                              void* d_out, int out_size, void* d_ws, size_t ws_size,
                              hipStream_t stream){
  const float* x      = (const float*)d_in[0];
  const float* norm_w = (const float*)d_in[1];
  const float* norm_b = (const float*)d_in[2];
  const float* qkv_w  = (const float*)d_in[3];
  const float* qkv_b  = (const float*)d_in[4];
  const float* proj_w = (const float*)d_in[5];
  const float* proj_b = (const float*)d_in[6];
  float* out = (float*)d_out;

  u16* h_t   = (u16*)d_ws;                                  // [16][1024][512]
  u16* qk_t  = h_t  + (size_t)16*1024*512;                  // [16][1024][1024]
  u16* v_ws  = qk_t + (size_t)16*1024*1024;                 // [16][512][1024]
  u16* wq_bf = v_ws + (size_t)16*512*1024;                  // [1536][512]
  u16* wp_bf = wq_bf + (size_t)1536*512;                    // [512][512]
  u16* attnout = h_t;                                       // reuse

  pre_kernel<<<1536, 256, 0, stream>>>(x, norm_w, norm_b, h_t,
                                       qkv_w, wq_bf, 1536*512, proj_w, wp_bf, 512*512);

  gemm_qkv_kernel<<<dim3(6,8,16), 256, 0, stream>>>(h_t, wq_bf, qkv_b, qk_t, v_ws);

  attn_kernel<<<512, 256, 0, stream>>>(qk_t, v_ws, attnout);

  gemm_bt_kernel<<<dim3(8,4,16), 256, 0, stream>>>(
      wp_bf, 0, attnout, (long long)1024*512,
      nullptr, out, (long long)512*1024, proj_b, nullptr, x, (long long)512*1024, 512, 1024, 512);
}